// Round 1
// baseline (712.820 us; speedup 1.0000x reference)
//
#include <hip/hip_runtime.h>
#include <hip/hip_bf16.h>
#include <cstdint>

#define NEG_SLOPE 0.2f

// ---------------- CSR build ----------------
__global__ void k_deg(const int* __restrict__ ei, int E, int n, unsigned* __restrict__ deg) {
    int e = blockIdx.x * blockDim.x + threadIdx.x;
    int ET = E + n;
    if (e >= ET) return;
    int d = (e < E) ? ei[E + e] : (e - E);
    atomicAdd(&deg[d], 1u);
}

__global__ void k_scan1(const unsigned* __restrict__ deg, int n,
                        unsigned* __restrict__ rowptr, unsigned* __restrict__ bsum) {
    __shared__ unsigned s[256];
    int tid = threadIdx.x;
    int i = blockIdx.x * 256 + tid;
    unsigned v = (i < n) ? deg[i] : 0u;
    s[tid] = v; __syncthreads();
    for (int off = 1; off < 256; off <<= 1) {
        unsigned t = (tid >= off) ? s[tid - off] : 0u;
        __syncthreads();
        s[tid] += t;
        __syncthreads();
    }
    if (i < n) rowptr[i + 1] = s[tid];  // inclusive scan, shifted
    if (tid == 255) bsum[blockIdx.x] = s[255];
}

__global__ void k_scan2(unsigned* __restrict__ bsum, int nb) {
    __shared__ unsigned s[256];
    int tid = threadIdx.x;
    unsigned v = (tid < nb) ? bsum[tid] : 0u;
    s[tid] = v; __syncthreads();
    for (int off = 1; off < 256; off <<= 1) {
        unsigned t = (tid >= off) ? s[tid - off] : 0u;
        __syncthreads();
        s[tid] += t;
        __syncthreads();
    }
    if (tid < nb) bsum[tid] = s[tid];  // inclusive
}

__global__ void k_scan3(unsigned* __restrict__ rowptr, const unsigned* __restrict__ bsum, int n) {
    int tid = threadIdx.x;
    int b = blockIdx.x;
    int i = b * 256 + tid;
    if (b == 0) {
        if (i == 0) rowptr[0] = 0u;
        return;
    }
    if (i < n) rowptr[i + 1] += bsum[b - 1];
}

__global__ void k_scatter(const int* __restrict__ ei, int E, int n,
                          unsigned* __restrict__ cursor, unsigned* __restrict__ csr_src) {
    int e = blockIdx.x * blockDim.x + threadIdx.x;
    int ET = E + n;
    if (e >= ET) return;
    int s, d;
    if (e < E) { s = ei[e]; d = ei[E + e]; } else { s = d = e - E; }
    unsigned pos = atomicAdd(&cursor[d], 1u);
    csr_src[pos] = (unsigned)s;
}

// ---------------- GEMM1: h1pre = x @ W1  [n,512] x [512,128] ----------------
__global__ __launch_bounds__(256) void k_gemm1(const float* __restrict__ x,
                                               const float* __restrict__ W1,
                                               float* __restrict__ h1pre, int n) {
    __shared__ float xs[16 * 512];  // 32 KB
    int tid = threadIdx.x;
    int bn = blockIdx.x * 16;
    const float4* x4 = (const float4*)x;
    float4* xs4 = (float4*)xs;
    for (int v = tid; v < 2048; v += 256) {      // 16 rows x 128 float4
        int r = v >> 7, c4 = v & 127;
        int node = bn + r;
        xs4[v] = (node < n) ? x4[(size_t)node * 128 + c4] : make_float4(0.f, 0.f, 0.f, 0.f);
    }
    __syncthreads();
    int j = tid & 127;
    int g = tid >> 7;  // 0..1, 8 rows each
    float acc[8] = {0.f, 0.f, 0.f, 0.f, 0.f, 0.f, 0.f, 0.f};
    for (int k4 = 0; k4 < 128; ++k4) {
        float w0 = W1[(size_t)(4 * k4 + 0) * 128 + j];
        float w1 = W1[(size_t)(4 * k4 + 1) * 128 + j];
        float w2 = W1[(size_t)(4 * k4 + 2) * 128 + j];
        float w3 = W1[(size_t)(4 * k4 + 3) * 128 + j];
        #pragma unroll
        for (int r = 0; r < 8; ++r) {
            float4 xv = xs4[(g * 8 + r) * 128 + k4];
            acc[r] += xv.x * w0 + xv.y * w1 + xv.z * w2 + xv.w * w3;
        }
    }
    #pragma unroll
    for (int r = 0; r < 8; ++r) {
        int node = bn + g * 8 + r;
        if (node < n) h1pre[(size_t)node * 128 + j] = acc[r];
    }
}

// ---------------- alpha1: per (node, head) dot(h1pre, a_src/a_dst) ----------------
__global__ void k_alpha1(const float* __restrict__ h1pre, const float* __restrict__ a_src,
                         const float* __restrict__ a_dst, float* __restrict__ asrc,
                         float* __restrict__ adst, int n) {
    int idx = blockIdx.x * blockDim.x + threadIdx.x;  // (i,h)
    if (idx >= n * 4) return;
    int i = idx >> 2, h = idx & 3;
    const float4* hp  = (const float4*)(h1pre + (size_t)i * 128 + h * 32);
    const float4* as4 = (const float4*)(a_src + h * 32);
    const float4* ad4 = (const float4*)(a_dst + h * 32);
    float ss = 0.f, dd = 0.f;
    #pragma unroll
    for (int q = 0; q < 8; ++q) {
        float4 hv = hp[q]; float4 av = as4[q]; float4 bv = ad4[q];
        ss += hv.x * av.x + hv.y * av.y + hv.z * av.z + hv.w * av.w;
        dd += hv.x * bv.x + hv.y * bv.y + hv.z * bv.z + hv.w * bv.w;
    }
    asrc[idx] = ss;
    adst[idx] = dd;
}

// ---------------- GAT1 aggregation: block per dst node, 128 threads ----------------
__global__ __launch_bounds__(128) void k_gat1(const float* __restrict__ h1pre,
                                              const float* __restrict__ asrc,
                                              const float* __restrict__ adst,
                                              const float* __restrict__ b1,
                                              const unsigned* __restrict__ rowptr,
                                              const unsigned* __restrict__ csr_src,
                                              float* __restrict__ h1, int n) {
    int d = blockIdx.x;
    int tid = threadIdx.x;
    int t = tid & 31, h = tid >> 5;  // roles: (t,h) for edge staging; c=tid for output
    unsigned k0 = rowptr[d], k1 = rowptr[d + 1];
    float adh = adst[d * 4 + h];
    __shared__ unsigned ss[32];
    __shared__ float ps[4 * 32];
    // sweep 1: per-head max
    float vmax = -3.0e38f;
    for (unsigned kk = k0; kk < k1; kk += 32) {
        unsigned k = kk + t;
        if (k < k1) {
            unsigned s = csr_src[k];
            float v = asrc[s * 4 + h] + adh;
            v = (v > 0.f) ? v : NEG_SLOPE * v;
            vmax = fmaxf(vmax, v);
        }
    }
    #pragma unroll
    for (int m = 16; m >= 1; m >>= 1) vmax = fmaxf(vmax, __shfl_xor(vmax, m, 32));
    // sweep 2: p = exp(v - max); accumulate numerator and denominator
    float den = 0.f, acc = 0.f;
    for (unsigned kk = k0; kk < k1; kk += 32) {
        unsigned k = kk + t;
        float p = 0.f; unsigned s = 0u;
        if (k < k1) {
            s = csr_src[k];
            float v = asrc[s * 4 + h] + adh;
            v = (v > 0.f) ? v : NEG_SLOPE * v;
            p = __expf(v - vmax);
        }
        if (h == 0) ss[t] = s;
        ps[h * 32 + t] = p;
        den += p;
        __syncthreads();
        int nk = (int)min(32u, k1 - kk);
        for (int q = 0; q < nk; ++q) {
            float pq = ps[h * 32 + q];                       // broadcast within head group
            acc = fmaf(pq, h1pre[(size_t)ss[q] * 128 + tid], acc);  // coalesced 512B row
        }
        __syncthreads();
    }
    #pragma unroll
    for (int m = 16; m >= 1; m >>= 1) den += __shfl_xor(den, m, 32);
    float o = acc / (den + 1e-16f) + b1[tid];
    h1[(size_t)d * 128 + tid] = (o > 0.f) ? o : (__expf(o) - 1.f);  // ELU
}

// ---------------- h2 = h1 @ W2 [n,128]x[128,32] + alpha2 reductions ----------------
__global__ __launch_bounds__(256) void k_h2(const float* __restrict__ h1,
                                            const float* __restrict__ W2,
                                            const float* __restrict__ a_src2,
                                            const float* __restrict__ a_dst2,
                                            float* __restrict__ h2,
                                            float* __restrict__ asrc2,
                                            float* __restrict__ adst2, int n) {
    __shared__ float hs[8 * 128];
    int tid = threadIdx.x;
    int bn = blockIdx.x * 8;
    const float4* h14 = (const float4*)h1;
    float4* hs4 = (float4*)hs;
    {
        int r = tid >> 5, c4 = tid & 31;
        int node = bn + r;
        hs4[tid] = (node < n) ? h14[(size_t)node * 32 + c4] : make_float4(0.f, 0.f, 0.f, 0.f);
    }
    __syncthreads();
    int j = tid & 31, r = tid >> 5;
    float acc = 0.f;
    #pragma unroll 8
    for (int k = 0; k < 128; ++k) {
        acc = fmaf(hs[r * 128 + k], W2[k * 32 + j], acc);
    }
    int node = bn + r;
    float cs = acc * a_src2[j];
    float cd = acc * a_dst2[j];
    #pragma unroll
    for (int m = 16; m >= 1; m >>= 1) {
        cs += __shfl_xor(cs, m, 32);
        cd += __shfl_xor(cd, m, 32);
    }
    if (node < n) {
        h2[(size_t)node * 32 + j] = acc;
        if (j == 0) { asrc2[node] = cs; adst2[node] = cd; }
    }
}

// ---------------- GAT2 aggregation: block (1 wave) per dst node ----------------
__global__ __launch_bounds__(64) void k_gat2(const float* __restrict__ h2,
                                             const float* __restrict__ asrc2,
                                             const float* __restrict__ adst2,
                                             const float* __restrict__ b2,
                                             const unsigned* __restrict__ rowptr,
                                             const unsigned* __restrict__ csr_src,
                                             float* __restrict__ g, int n) {
    int d = blockIdx.x;
    int tid = threadIdx.x;
    unsigned k0 = rowptr[d], k1 = rowptr[d + 1];
    float adh = adst2[d];
    __shared__ unsigned ss[64];
    __shared__ float ps[64];
    float vmax = -3.0e38f;
    for (unsigned kk = k0; kk < k1; kk += 64) {
        unsigned k = kk + tid;
        if (k < k1) {
            float v = asrc2[csr_src[k]] + adh;
            v = (v > 0.f) ? v : NEG_SLOPE * v;
            vmax = fmaxf(vmax, v);
        }
    }
    #pragma unroll
    for (int m = 32; m >= 1; m >>= 1) vmax = fmaxf(vmax, __shfl_xor(vmax, m, 64));
    float den = 0.f, acc = 0.f;
    int c = tid & 31, half = tid >> 5;
    for (unsigned kk = k0; kk < k1; kk += 64) {
        unsigned k = kk + tid;
        float p = 0.f; unsigned s = 0u;
        if (k < k1) {
            s = csr_src[k];
            float v = asrc2[s] + adh;
            v = (v > 0.f) ? v : NEG_SLOPE * v;
            p = __expf(v - vmax);
        }
        ss[tid] = s; ps[tid] = p;
        den += p;
        __syncthreads();
        int nk = (int)min(64u, k1 - kk);
        for (int q = half; q < nk; q += 2) {
            acc = fmaf(ps[q], h2[(size_t)ss[q] * 32 + c], acc);
        }
        __syncthreads();
    }
    #pragma unroll
    for (int m = 32; m >= 1; m >>= 1) den += __shfl_xor(den, m, 64);
    acc += __shfl_xor(acc, 32, 64);
    if (tid < 32) g[(size_t)d * 32 + c] = acc / (den + 1e-16f) + b2[c];
}

// ---------------- fused final MLP: out = relu([txt,g]@Wf1+bf1)@Wf2+bf2 ----------------
__global__ __launch_bounds__(256) void k_mlp(const float* __restrict__ txt,
                                             const float* __restrict__ g,
                                             const float* __restrict__ Wf1,
                                             const float* __restrict__ bf1,
                                             const float* __restrict__ Wf2,
                                             const float* __restrict__ bf2,
                                             float* __restrict__ out, int n) {
    __shared__ float zs[16 * 800];  // 51.2 KB
    int tid = threadIdx.x;
    int bn = blockIdx.x * 16;
    const float4* t4 = (const float4*)txt;
    for (int v = tid; v < 3072; v += 256) {   // 16 rows x 192 float4 of txt
        int r = v / 192, c4 = v % 192;
        int node = bn + r;
        float4 val = (node < n) ? t4[(size_t)node * 192 + c4] : make_float4(0.f, 0.f, 0.f, 0.f);
        float* dstp = &zs[r * 800 + c4 * 4];
        dstp[0] = val.x; dstp[1] = val.y; dstp[2] = val.z; dstp[3] = val.w;
    }
    const float4* g4 = (const float4*)g;
    if (tid < 128) {                           // 16 rows x 8 float4 of g
        int r = tid >> 3, c4 = tid & 7;
        int node = bn + r;
        float4 val = (node < n) ? g4[(size_t)node * 8 + c4] : make_float4(0.f, 0.f, 0.f, 0.f);
        float* dstp = &zs[r * 800 + 768 + c4 * 4];
        dstp[0] = val.x; dstp[1] = val.y; dstp[2] = val.z; dstp[3] = val.w;
    }
    __syncthreads();
    int j = tid & 63, grp = tid >> 6;  // wave grp handles nodes grp*4 .. grp*4+3
    float acc0 = 0.f, acc1 = 0.f, acc2 = 0.f, acc3 = 0.f;
    for (int k4 = 0; k4 < 200; ++k4) {
        float w0 = Wf1[(size_t)(4 * k4 + 0) * 64 + j];
        float w1 = Wf1[(size_t)(4 * k4 + 1) * 64 + j];
        float w2 = Wf1[(size_t)(4 * k4 + 2) * 64 + j];
        float w3 = Wf1[(size_t)(4 * k4 + 3) * 64 + j];
        float4 z0 = *(const float4*)&zs[(grp * 4 + 0) * 800 + 4 * k4];
        float4 z1 = *(const float4*)&zs[(grp * 4 + 1) * 800 + 4 * k4];
        float4 z2 = *(const float4*)&zs[(grp * 4 + 2) * 800 + 4 * k4];
        float4 z3 = *(const float4*)&zs[(grp * 4 + 3) * 800 + 4 * k4];
        acc0 += z0.x * w0 + z0.y * w1 + z0.z * w2 + z0.w * w3;
        acc1 += z1.x * w0 + z1.y * w1 + z1.z * w2 + z1.w * w3;
        acc2 += z2.x * w0 + z2.y * w1 + z2.z * w2 + z2.w * w3;
        acc3 += z3.x * w0 + z3.y * w1 + z3.z * w2 + z3.w * w3;
    }
    float b = bf1[j], w = Wf2[j];
    float r0 = fmaxf(acc0 + b, 0.f) * w;
    float r1 = fmaxf(acc1 + b, 0.f) * w;
    float r2 = fmaxf(acc2 + b, 0.f) * w;
    float r3 = fmaxf(acc3 + b, 0.f) * w;
    #pragma unroll
    for (int m = 32; m >= 1; m >>= 1) {
        r0 += __shfl_xor(r0, m, 64);
        r1 += __shfl_xor(r1, m, 64);
        r2 += __shfl_xor(r2, m, 64);
        r3 += __shfl_xor(r3, m, 64);
    }
    if (j == 0) {
        float bb = bf2[0];
        int base = bn + grp * 4;
        if (base + 0 < n) out[base + 0] = r0 + bb;
        if (base + 1 < n) out[base + 1] = r1 + bb;
        if (base + 2 < n) out[base + 2] = r2 + bb;
        if (base + 3 < n) out[base + 3] = r3 + bb;
    }
}

extern "C" void kernel_launch(void* const* d_in, const int* in_sizes, int n_in,
                              void* d_out, int out_size, void* d_ws, size_t ws_size,
                              hipStream_t stream) {
    const float* txt    = (const float*)d_in[0];
    const float* x      = (const float*)d_in[1];
    const float* W1     = (const float*)d_in[2];
    const float* a_src1 = (const float*)d_in[3];
    const float* a_dst1 = (const float*)d_in[4];
    const float* b1     = (const float*)d_in[5];
    const float* W2     = (const float*)d_in[6];
    const float* a_src2 = (const float*)d_in[7];
    const float* a_dst2 = (const float*)d_in[8];
    const float* b2     = (const float*)d_in[9];
    const float* Wf1    = (const float*)d_in[10];
    const float* bf1    = (const float*)d_in[11];
    const float* Wf2    = (const float*)d_in[12];
    const float* bf2    = (const float*)d_in[13];
    const int*   ei     = (const int*)d_in[14];

    int n  = in_sizes[1] / 512;
    int E  = in_sizes[14] / 2;
    int ET = E + n;
    float* out = (float*)d_out;

    char* p = (char*)d_ws;
    auto alloc = [&](size_t bytes) -> char* {
        char* q = p;
        p += (bytes + 255) & ~(size_t)255;
        return q;
    };
    float*    h1pre  = (float*)alloc((size_t)n * 128 * 4);
    float*    h1     = (float*)alloc((size_t)n * 128 * 4);
    float*    asrc1  = (float*)alloc((size_t)n * 4 * 4);
    float*    adst1  = (float*)alloc((size_t)n * 4 * 4);
    float*    h2     = (float*)alloc((size_t)n * 32 * 4);
    float*    asrc2  = (float*)alloc((size_t)n * 4);
    float*    adst2  = (float*)alloc((size_t)n * 4);
    float*    gbuf   = (float*)alloc((size_t)n * 32 * 4);
    unsigned* deg    = (unsigned*)alloc((size_t)n * 4);
    unsigned* rowptr = (unsigned*)alloc((size_t)(n + 1) * 4);
    unsigned* cursor = (unsigned*)alloc((size_t)n * 4);
    unsigned* bsum   = (unsigned*)alloc(256 * 4);
    unsigned* csr    = (unsigned*)alloc((size_t)ET * 4);

    hipMemsetAsync(deg, 0, (size_t)n * 4, stream);
    int tb = 256;
    int nbE = (ET + tb - 1) / tb;
    k_deg<<<nbE, tb, 0, stream>>>(ei, E, n, deg);
    int nb = (n + 255) / 256;
    k_scan1<<<nb, 256, 0, stream>>>(deg, n, rowptr, bsum);
    k_scan2<<<1, 256, 0, stream>>>(bsum, nb);
    k_scan3<<<nb, 256, 0, stream>>>(rowptr, bsum, n);
    hipMemcpyAsync(cursor, rowptr, (size_t)n * 4, hipMemcpyDeviceToDevice, stream);
    k_scatter<<<nbE, tb, 0, stream>>>(ei, E, n, cursor, csr);

    k_gemm1<<<(n + 15) / 16, 256, 0, stream>>>(x, W1, h1pre, n);
    k_alpha1<<<(n * 4 + 255) / 256, 256, 0, stream>>>(h1pre, a_src1, a_dst1, asrc1, adst1, n);
    k_gat1<<<n, 128, 0, stream>>>(h1pre, asrc1, adst1, b1, rowptr, csr, h1, n);
    k_h2<<<(n + 7) / 8, 256, 0, stream>>>(h1, W2, a_src2, a_dst2, h2, asrc2, adst2, n);
    k_gat2<<<n, 64, 0, stream>>>(h2, asrc2, adst2, b2, rowptr, csr, gbuf, n);
    k_mlp<<<(n + 15) / 16, 256, 0, stream>>>(txt, gbuf, Wf1, bf1, Wf2, bf2, out, n);
}

// Round 2
// 493.281 us; speedup vs baseline: 1.4451x; 1.4451x over previous
//
#include <hip/hip_runtime.h>
#include <hip/hip_bf16.h>
#include <cstdint>

#define NEG_SLOPE 0.2f

typedef __bf16 bf16_t;
typedef __bf16 bf16x8 __attribute__((ext_vector_type(8)));
typedef float f32x4 __attribute__((ext_vector_type(4)));

// ---------------- CSR build ----------------
__global__ void k_deg(const int* __restrict__ ei, int E, int n, unsigned* __restrict__ deg) {
    int e = blockIdx.x * blockDim.x + threadIdx.x;
    int ET = E + n;
    if (e >= ET) return;
    int d = (e < E) ? ei[E + e] : (e - E);
    atomicAdd(&deg[d], 1u);
}

__global__ void k_scan1(const unsigned* __restrict__ deg, int n,
                        unsigned* __restrict__ rowptr, unsigned* __restrict__ bsum) {
    __shared__ unsigned s[256];
    int tid = threadIdx.x;
    int i = blockIdx.x * 256 + tid;
    unsigned v = (i < n) ? deg[i] : 0u;
    s[tid] = v; __syncthreads();
    for (int off = 1; off < 256; off <<= 1) {
        unsigned t = (tid >= off) ? s[tid - off] : 0u;
        __syncthreads();
        s[tid] += t;
        __syncthreads();
    }
    if (i < n) rowptr[i + 1] = s[tid];
    if (tid == 255) bsum[blockIdx.x] = s[255];
}

__global__ void k_scan2(unsigned* __restrict__ bsum, int nb) {
    __shared__ unsigned s[256];
    int tid = threadIdx.x;
    unsigned v = (tid < nb) ? bsum[tid] : 0u;
    s[tid] = v; __syncthreads();
    for (int off = 1; off < 256; off <<= 1) {
        unsigned t = (tid >= off) ? s[tid - off] : 0u;
        __syncthreads();
        s[tid] += t;
        __syncthreads();
    }
    if (tid < nb) bsum[tid] = s[tid];
}

__global__ void k_scan3(unsigned* __restrict__ rowptr, const unsigned* __restrict__ bsum, int n) {
    int tid = threadIdx.x;
    int b = blockIdx.x;
    int i = b * 256 + tid;
    if (b == 0) {
        if (i == 0) rowptr[0] = 0u;
        return;
    }
    if (i < n) rowptr[i + 1] += bsum[b - 1];
}

__global__ void k_scatter(const int* __restrict__ ei, int E, int n,
                          unsigned* __restrict__ cursor, unsigned* __restrict__ csr_src) {
    int e = blockIdx.x * blockDim.x + threadIdx.x;
    int ET = E + n;
    if (e >= ET) return;
    int s, d;
    if (e < E) { s = ei[e]; d = ei[E + e]; } else { s = d = e - E; }
    unsigned pos = atomicAdd(&cursor[d], 1u);
    csr_src[pos] = (unsigned)s;
}

// ---------------- weight pre-transpose + bf16 convert ----------------
// W1 [512][128] f32 -> W1bt [128][512] bf16
__global__ __launch_bounds__(256) void k_w1t(const float* __restrict__ W, bf16_t* __restrict__ Wt) {
    __shared__ float s[16][17];
    int tx = threadIdx.x & 15, ty = threadIdx.x >> 4;
    int kt = blockIdx.x & 31, nt = blockIdx.x >> 5;  // 32 k-tiles, 8 n-tiles
    s[ty][tx] = W[(size_t)(kt * 16 + ty) * 128 + nt * 16 + tx];
    __syncthreads();
    Wt[(size_t)(nt * 16 + ty) * 512 + kt * 16 + tx] = (bf16_t)s[tx][ty];
}

// Wf1 [800][64] f32 -> Wf1bt [64][832] bf16 (zero-padded K 800..831)
__global__ __launch_bounds__(256) void k_wf1t(const float* __restrict__ W, bf16_t* __restrict__ Wt) {
    __shared__ float s[16][17];
    int tx = threadIdx.x & 15, ty = threadIdx.x >> 4;
    int kt = blockIdx.x % 52, nt = blockIdx.x / 52;  // 52 k-tiles, 4 n-tiles
    int kg = kt * 16 + ty;
    s[ty][tx] = (kg < 800) ? W[(size_t)kg * 64 + nt * 16 + tx] : 0.f;
    __syncthreads();
    Wt[(size_t)(nt * 16 + ty) * 832 + kt * 16 + tx] = (bf16_t)s[tx][ty];
}

__device__ __forceinline__ uint2 pack4bf16(float4 v) {
    ushort u0 = __builtin_bit_cast(ushort, (bf16_t)v.x);
    ushort u1 = __builtin_bit_cast(ushort, (bf16_t)v.y);
    ushort u2 = __builtin_bit_cast(ushort, (bf16_t)v.z);
    ushort u3 = __builtin_bit_cast(ushort, (bf16_t)v.w);
    uint2 r;
    r.x = (uint)u0 | ((uint)u1 << 16);
    r.y = (uint)u2 | ((uint)u3 << 16);
    return r;
}

// ---------------- GEMM1 (MFMA): h1pre = x @ W1  [n,512]x[512,128] ----------------
// block: 256 thr = 4 waves; tile M=64 N=128 BK=64; wave w -> M rows [16w,16w+16) x N=128
__global__ __launch_bounds__(256) void k_gemm1_mfma(const float* __restrict__ x,
                                                    const bf16_t* __restrict__ W1bt,
                                                    float* __restrict__ h1pre, int n) {
    __shared__ char lds[24576];           // As [64][64]bf16 (8KB) | Bs [128][64]bf16 (16KB)
    char* As = lds;
    char* Bs = lds + 8192;
    int tid = threadIdx.x;
    int bn = blockIdx.x * 64;
    int wave = tid >> 6, lane = tid & 63;
    int lr = lane & 15, lk = lane >> 4;
    f32x4 acc[8] = {};
    const float4* x4 = (const float4*)x;

    for (int s = 0; s < 8; ++s) {
        int k0 = s * 64;
        // stage A: 64 rows x 64 k (f32 -> bf16), 1024 float4 loads
        #pragma unroll
        for (int i = 0; i < 4; ++i) {
            int v = tid + i * 256;
            int row = v >> 4, c4 = v & 15;
            int node = bn + row;
            float4 val = (node < n) ? x4[(size_t)node * 128 + (k0 >> 2) + c4]
                                    : make_float4(0.f, 0.f, 0.f, 0.f);
            uint off = (uint)(row * 128 + c4 * 8);
            off ^= (uint)((row & 7) << 4);
            *(uint2*)(As + off) = pack4bf16(val);
        }
        // stage B: 128 rows x 64 k bf16, 2048 8B chunks
        #pragma unroll
        for (int i = 0; i < 8; ++i) {
            int v = tid + i * 256;
            int row = v >> 4, c = v & 15;
            uint2 val = *(const uint2*)(W1bt + (size_t)row * 512 + k0 + c * 4);
            uint off = (uint)(row * 128 + c * 8);
            off ^= (uint)((row & 7) << 4);
            *(uint2*)(Bs + off) = val;
        }
        __syncthreads();
        #pragma unroll
        for (int ks = 0; ks < 2; ++ks) {
            uint arow = (uint)(wave * 16 + lr);
            uint aoff = (arow * 128 + (uint)(ks * 64 + lk * 16)) ^ (uint)((lr & 7) << 4);
            bf16x8 av = *(const bf16x8*)(As + aoff);
            #pragma unroll
            for (int f = 0; f < 8; ++f) {
                uint brow = (uint)(f * 16 + lr);
                uint boff = (brow * 128 + (uint)(ks * 64 + lk * 16)) ^ (uint)((lr & 7) << 4);
                bf16x8 bv = *(const bf16x8*)(Bs + boff);
                acc[f] = __builtin_amdgcn_mfma_f32_16x16x32_bf16(av, bv, acc[f], 0, 0, 0);
            }
        }
        __syncthreads();
    }
    // epilogue: C/D layout col=lane&15, row=(lane>>4)*4+reg
    #pragma unroll
    for (int f = 0; f < 8; ++f) {
        int nn = f * 16 + lr;
        #pragma unroll
        for (int r = 0; r < 4; ++r) {
            int node = bn + wave * 16 + lk * 4 + r;
            if (node < n) h1pre[(size_t)node * 128 + nn] = acc[f][r];
        }
    }
}

// ---------------- alpha1 ----------------
__global__ void k_alpha1(const float* __restrict__ h1pre, const float* __restrict__ a_src,
                         const float* __restrict__ a_dst, float* __restrict__ asrc,
                         float* __restrict__ adst, int n) {
    int idx = blockIdx.x * blockDim.x + threadIdx.x;
    if (idx >= n * 4) return;
    int i = idx >> 2, h = idx & 3;
    const float4* hp  = (const float4*)(h1pre + (size_t)i * 128 + h * 32);
    const float4* as4 = (const float4*)(a_src + h * 32);
    const float4* ad4 = (const float4*)(a_dst + h * 32);
    float ss = 0.f, dd = 0.f;
    #pragma unroll
    for (int q = 0; q < 8; ++q) {
        float4 hv = hp[q]; float4 av = as4[q]; float4 bv = ad4[q];
        ss += hv.x * av.x + hv.y * av.y + hv.z * av.z + hv.w * av.w;
        dd += hv.x * bv.x + hv.y * bv.y + hv.z * bv.z + hv.w * bv.w;
    }
    asrc[idx] = ss;
    adst[idx] = dd;
}

// ---------------- GAT1 aggregation ----------------
__global__ __launch_bounds__(128) void k_gat1(const float* __restrict__ h1pre,
                                              const float* __restrict__ asrc,
                                              const float* __restrict__ adst,
                                              const float* __restrict__ b1,
                                              const unsigned* __restrict__ rowptr,
                                              const unsigned* __restrict__ csr_src,
                                              float* __restrict__ h1, int n) {
    int d = blockIdx.x;
    int tid = threadIdx.x;
    int t = tid & 31, h = tid >> 5;
    unsigned k0 = rowptr[d], k1 = rowptr[d + 1];
    float adh = adst[d * 4 + h];
    __shared__ unsigned ss[32];
    __shared__ float ps[4 * 32];
    float vmax = -3.0e38f;
    for (unsigned kk = k0; kk < k1; kk += 32) {
        unsigned k = kk + t;
        if (k < k1) {
            unsigned s = csr_src[k];
            float v = asrc[s * 4 + h] + adh;
            v = (v > 0.f) ? v : NEG_SLOPE * v;
            vmax = fmaxf(vmax, v);
        }
    }
    #pragma unroll
    for (int m = 16; m >= 1; m >>= 1) vmax = fmaxf(vmax, __shfl_xor(vmax, m, 32));
    float den = 0.f, acc = 0.f;
    for (unsigned kk = k0; kk < k1; kk += 32) {
        unsigned k = kk + t;
        float p = 0.f; unsigned s = 0u;
        if (k < k1) {
            s = csr_src[k];
            float v = asrc[s * 4 + h] + adh;
            v = (v > 0.f) ? v : NEG_SLOPE * v;
            p = __expf(v - vmax);
        }
        if (h == 0) ss[t] = s;
        ps[h * 32 + t] = p;
        den += p;
        __syncthreads();
        int nk = (int)min(32u, k1 - kk);
        for (int q = 0; q < nk; ++q) {
            float pq = ps[h * 32 + q];
            acc = fmaf(pq, h1pre[(size_t)ss[q] * 128 + tid], acc);
        }
        __syncthreads();
    }
    #pragma unroll
    for (int m = 16; m >= 1; m >>= 1) den += __shfl_xor(den, m, 32);
    float o = acc / (den + 1e-16f) + b1[tid];
    h1[(size_t)d * 128 + tid] = (o > 0.f) ? o : (__expf(o) - 1.f);
}

// ---------------- h2 = h1 @ W2 + alpha2 ----------------
__global__ __launch_bounds__(256) void k_h2(const float* __restrict__ h1,
                                            const float* __restrict__ W2,
                                            const float* __restrict__ a_src2,
                                            const float* __restrict__ a_dst2,
                                            float* __restrict__ h2,
                                            float* __restrict__ asrc2,
                                            float* __restrict__ adst2, int n) {
    __shared__ float hs[8 * 128];
    int tid = threadIdx.x;
    int bn = blockIdx.x * 8;
    const float4* h14 = (const float4*)h1;
    float4* hs4 = (float4*)hs;
    {
        int r = tid >> 5, c4 = tid & 31;
        int node = bn + r;
        hs4[tid] = (node < n) ? h14[(size_t)node * 32 + c4] : make_float4(0.f, 0.f, 0.f, 0.f);
    }
    __syncthreads();
    int j = tid & 31, r = tid >> 5;
    float acc = 0.f;
    #pragma unroll 8
    for (int k = 0; k < 128; ++k) {
        acc = fmaf(hs[r * 128 + k], W2[k * 32 + j], acc);
    }
    int node = bn + r;
    float cs = acc * a_src2[j];
    float cd = acc * a_dst2[j];
    #pragma unroll
    for (int m = 16; m >= 1; m >>= 1) {
        cs += __shfl_xor(cs, m, 32);
        cd += __shfl_xor(cd, m, 32);
    }
    if (node < n) {
        h2[(size_t)node * 32 + j] = acc;
        if (j == 0) { asrc2[node] = cs; adst2[node] = cd; }
    }
}

// ---------------- GAT2 aggregation ----------------
__global__ __launch_bounds__(64) void k_gat2(const float* __restrict__ h2,
                                             const float* __restrict__ asrc2,
                                             const float* __restrict__ adst2,
                                             const float* __restrict__ b2,
                                             const unsigned* __restrict__ rowptr,
                                             const unsigned* __restrict__ csr_src,
                                             float* __restrict__ g, int n) {
    int d = blockIdx.x;
    int tid = threadIdx.x;
    unsigned k0 = rowptr[d], k1 = rowptr[d + 1];
    float adh = adst2[d];
    __shared__ unsigned ss[64];
    __shared__ float ps[64];
    float vmax = -3.0e38f;
    for (unsigned kk = k0; kk < k1; kk += 64) {
        unsigned k = kk + tid;
        if (k < k1) {
            float v = asrc2[csr_src[k]] + adh;
            v = (v > 0.f) ? v : NEG_SLOPE * v;
            vmax = fmaxf(vmax, v);
        }
    }
    #pragma unroll
    for (int m = 32; m >= 1; m >>= 1) vmax = fmaxf(vmax, __shfl_xor(vmax, m, 64));
    float den = 0.f, acc = 0.f;
    int c = tid & 31, half = tid >> 5;
    for (unsigned kk = k0; kk < k1; kk += 64) {
        unsigned k = kk + tid;
        float p = 0.f; unsigned s = 0u;
        if (k < k1) {
            s = csr_src[k];
            float v = asrc2[s] + adh;
            v = (v > 0.f) ? v : NEG_SLOPE * v;
            p = __expf(v - vmax);
        }
        ss[tid] = s; ps[tid] = p;
        den += p;
        __syncthreads();
        int nk = (int)min(64u, k1 - kk);
        for (int q = half; q < nk; q += 2) {
            acc = fmaf(ps[q], h2[(size_t)ss[q] * 32 + c], acc);
        }
        __syncthreads();
    }
    #pragma unroll
    for (int m = 32; m >= 1; m >>= 1) den += __shfl_xor(den, m, 64);
    acc += __shfl_xor(acc, 32, 64);
    if (tid < 32) g[(size_t)d * 32 + c] = acc / (den + 1e-16f) + b2[c];
}

// ---------------- MLP (MFMA): out = relu([txt,g]@Wf1+bf1)@Wf2+bf2 ----------------
// M=n, N=64, K=800 (padded 832). block: 4 waves, tile M=64 N=64 BK=64.
__global__ __launch_bounds__(256) void k_mlp_mfma(const float* __restrict__ txt,
                                                  const float* __restrict__ g,
                                                  const bf16_t* __restrict__ Wf1bt,
                                                  const float* __restrict__ bf1,
                                                  const float* __restrict__ Wf2,
                                                  const float* __restrict__ bf2,
                                                  float* __restrict__ out, int n) {
    __shared__ char lds[16384];           // As [64][64]bf16 | Bs [64][64]bf16
    char* As = lds;
    char* Bs = lds + 8192;
    int tid = threadIdx.x;
    int bn = blockIdx.x * 64;
    int wave = tid >> 6, lane = tid & 63;
    int lr = lane & 15, lk = lane >> 4;
    f32x4 acc[4] = {};
    const float4* t4 = (const float4*)txt;
    const float4* g4 = (const float4*)g;

    for (int s = 0; s < 13; ++s) {
        int k0 = s * 64;
        // stage A (z-tile): cols <768 from txt, 768..799 from g, >=800 zero
        #pragma unroll
        for (int i = 0; i < 4; ++i) {
            int v = tid + i * 256;
            int row = v >> 4, c4 = v & 15;
            int node = bn + row;
            int kg = k0 + c4 * 4;
            float4 val = make_float4(0.f, 0.f, 0.f, 0.f);
            if (node < n) {
                if (kg < 768)      val = t4[(size_t)node * 192 + (kg >> 2)];
                else if (kg < 800) val = g4[(size_t)node * 8 + ((kg - 768) >> 2)];
            }
            uint off = (uint)(row * 128 + c4 * 8);
            off ^= (uint)((row & 7) << 4);
            *(uint2*)(As + off) = pack4bf16(val);
        }
        // stage B: Wf1bt rows 0..63, 64 k (stride 832)
        #pragma unroll
        for (int i = 0; i < 4; ++i) {
            int v = tid + i * 256;
            int row = v >> 4, c = v & 15;
            uint2 val = *(const uint2*)(Wf1bt + (size_t)row * 832 + k0 + c * 4);
            uint off = (uint)(row * 128 + c * 8);
            off ^= (uint)((row & 7) << 4);
            *(uint2*)(Bs + off) = val;
        }
        __syncthreads();
        #pragma unroll
        for (int ks = 0; ks < 2; ++ks) {
            uint arow = (uint)(wave * 16 + lr);
            uint aoff = (arow * 128 + (uint)(ks * 64 + lk * 16)) ^ (uint)((lr & 7) << 4);
            bf16x8 av = *(const bf16x8*)(As + aoff);
            #pragma unroll
            for (int f = 0; f < 4; ++f) {
                uint brow = (uint)(f * 16 + lr);
                uint boff = (brow * 128 + (uint)(ks * 64 + lk * 16)) ^ (uint)((lr & 7) << 4);
                bf16x8 bv = *(const bf16x8*)(Bs + boff);
                acc[f] = __builtin_amdgcn_mfma_f32_16x16x32_bf16(av, bv, acc[f], 0, 0, 0);
            }
        }
        __syncthreads();
    }
    // fused epilogue: relu(acc + bf1)*Wf2, row-sum over N=64, + bf2
    float rsum[4] = {0.f, 0.f, 0.f, 0.f};
    #pragma unroll
    for (int f = 0; f < 4; ++f) {
        int nn = f * 16 + lr;
        float bb = bf1[nn], ww = Wf2[nn];
        #pragma unroll
        for (int r = 0; r < 4; ++r) {
            float v = acc[f][r] + bb;
            rsum[r] += fmaxf(v, 0.f) * ww;
        }
    }
    #pragma unroll
    for (int r = 0; r < 4; ++r) {
        #pragma unroll
        for (int m = 8; m >= 1; m >>= 1) rsum[r] += __shfl_xor(rsum[r], m, 64);
        if (lr == 0) {
            int node = bn + wave * 16 + lk * 4 + r;
            if (node < n) out[node] = rsum[r] + bf2[0];
        }
    }
}

extern "C" void kernel_launch(void* const* d_in, const int* in_sizes, int n_in,
                              void* d_out, int out_size, void* d_ws, size_t ws_size,
                              hipStream_t stream) {
    const float* txt    = (const float*)d_in[0];
    const float* x      = (const float*)d_in[1];
    const float* W1     = (const float*)d_in[2];
    const float* a_src1 = (const float*)d_in[3];
    const float* a_dst1 = (const float*)d_in[4];
    const float* b1     = (const float*)d_in[5];
    const float* W2     = (const float*)d_in[6];
    const float* a_src2 = (const float*)d_in[7];
    const float* a_dst2 = (const float*)d_in[8];
    const float* b2     = (const float*)d_in[9];
    const float* Wf1    = (const float*)d_in[10];
    const float* bf1    = (const float*)d_in[11];
    const float* Wf2    = (const float*)d_in[12];
    const float* bf2    = (const float*)d_in[13];
    const int*   ei     = (const int*)d_in[14];

    int n  = in_sizes[1] / 512;
    int E  = in_sizes[14] / 2;
    int ET = E + n;
    float* out = (float*)d_out;

    char* p = (char*)d_ws;
    auto alloc = [&](size_t bytes) -> char* {
        char* q = p;
        p += (bytes + 255) & ~(size_t)255;
        return q;
    };
    float*    h1pre  = (float*)alloc((size_t)n * 128 * 4);
    float*    h1     = (float*)alloc((size_t)n * 128 * 4);
    float*    asrc1  = (float*)alloc((size_t)n * 4 * 4);
    float*    adst1  = (float*)alloc((size_t)n * 4 * 4);
    float*    h2     = (float*)alloc((size_t)n * 32 * 4);
    float*    asrc2  = (float*)alloc((size_t)n * 4);
    float*    adst2  = (float*)alloc((size_t)n * 4);
    float*    gbuf   = (float*)alloc((size_t)n * 32 * 4);
    unsigned* deg    = (unsigned*)alloc((size_t)n * 4);
    unsigned* rowptr = (unsigned*)alloc((size_t)(n + 1) * 4);
    unsigned* cursor = (unsigned*)alloc((size_t)n * 4);
    unsigned* bsum   = (unsigned*)alloc(256 * 4);
    unsigned* csr    = (unsigned*)alloc((size_t)ET * 4);
    bf16_t*   W1bt   = (bf16_t*)alloc((size_t)128 * 512 * 2);
    bf16_t*   Wf1bt  = (bf16_t*)alloc((size_t)64 * 832 * 2);

    hipMemsetAsync(deg, 0, (size_t)n * 4, stream);
    int tb = 256;
    int nbE = (ET + tb - 1) / tb;
    k_deg<<<nbE, tb, 0, stream>>>(ei, E, n, deg);
    int nb = (n + 255) / 256;
    k_scan1<<<nb, 256, 0, stream>>>(deg, n, rowptr, bsum);
    k_scan2<<<1, 256, 0, stream>>>(bsum, nb);
    k_scan3<<<nb, 256, 0, stream>>>(rowptr, bsum, n);
    hipMemcpyAsync(cursor, rowptr, (size_t)n * 4, hipMemcpyDeviceToDevice, stream);
    k_scatter<<<nbE, tb, 0, stream>>>(ei, E, n, cursor, csr);

    k_w1t<<<256, 256, 0, stream>>>(W1, W1bt);
    k_wf1t<<<208, 256, 0, stream>>>(Wf1, Wf1bt);

    int nb64 = (n + 63) / 64;
    k_gemm1_mfma<<<nb64, 256, 0, stream>>>(x, W1bt, h1pre, n);
    k_alpha1<<<(n * 4 + 255) / 256, 256, 0, stream>>>(h1pre, a_src1, a_dst1, asrc1, adst1, n);
    k_gat1<<<n, 128, 0, stream>>>(h1pre, asrc1, adst1, b1, rowptr, csr, h1, n);
    k_h2<<<(n + 7) / 8, 256, 0, stream>>>(h1, W2, a_src2, a_dst2, h2, asrc2, adst2, n);
    k_gat2<<<n, 64, 0, stream>>>(h2, asrc2, adst2, b2, rowptr, csr, gbuf, n);
    k_mlp_mfma<<<nb64, 256, 0, stream>>>(txt, gbuf, Wf1bt, bf1, Wf2, bf2, out, n);
}

// Round 3
// 293.664 us; speedup vs baseline: 2.4273x; 1.6797x over previous
//
#include <hip/hip_runtime.h>
#include <hip/hip_bf16.h>
#include <cstdint>

#define NEG_SLOPE 0.2f
#define BCAP 16384

typedef __bf16 bf16_t;
typedef __bf16 bf16x8 __attribute__((ext_vector_type(8)));
typedef float f32x4 __attribute__((ext_vector_type(4)));

__device__ __forceinline__ uint2 pack4bf16(float4 v) {
    ushort u0 = __builtin_bit_cast(ushort, (bf16_t)v.x);
    ushort u1 = __builtin_bit_cast(ushort, (bf16_t)v.y);
    ushort u2 = __builtin_bit_cast(ushort, (bf16_t)v.z);
    ushort u3 = __builtin_bit_cast(ushort, (bf16_t)v.w);
    uint2 r;
    r.x = (uint)u0 | ((uint)u1 << 16);
    r.y = (uint)u2 | ((uint)u3 << 16);
    return r;
}

__device__ __forceinline__ float bflo(uint u) { return __builtin_bit_cast(float, u << 16); }
__device__ __forceinline__ float bfhi(uint u) { return __builtin_bit_cast(float, u & 0xFFFF0000u); }

// ---------------- bucket pass 1: group edges by dst>>8 into per-bucket regions ----------------
// block = 256 thr, one 4096-edge tile per block. Packed entry: (d<<16)|s (both < 65536).
__global__ __launch_bounds__(256) void k_bucket(const int* __restrict__ ei, int E, int n,
                                                int nbuck, unsigned* __restrict__ gcur,
                                                unsigned* __restrict__ gbuck) {
    __shared__ unsigned stage[4096];
    __shared__ unsigned cnt[256], sc[256], offx[256], gbase[256];
    int tid = threadIdx.x;
    int ET = E + n;
    int tileStart = blockIdx.x * 4096;
    cnt[tid] = 0;
    __syncthreads();
    unsigned pk[16];
    int rk[16];
    #pragma unroll
    for (int i = 0; i < 16; ++i) {
        int idx = tileStart + i * 256 + tid;
        rk[i] = -1;
        if (idx < ET) {
            int s, d;
            if (idx < E) { s = ei[idx]; d = ei[E + idx]; } else { s = d = idx - E; }
            pk[i] = ((unsigned)d << 16) | (unsigned)s;
            rk[i] = (int)atomicAdd(&cnt[(unsigned)d >> 8], 1u);
        }
    }
    __syncthreads();
    sc[tid] = cnt[tid];
    __syncthreads();
    for (int off = 1; off < 256; off <<= 1) {
        unsigned t = (tid >= off) ? sc[tid - off] : 0u;
        __syncthreads();
        sc[tid] += t;
        __syncthreads();
    }
    offx[tid] = sc[tid] - cnt[tid];
    if (tid < nbuck && cnt[tid] > 0) gbase[tid] = atomicAdd(&gcur[tid], cnt[tid]);
    unsigned total = sc[255];
    __syncthreads();
    #pragma unroll
    for (int i = 0; i < 16; ++i) {
        if (rk[i] >= 0) stage[offx[pk[i] >> 24] + rk[i]] = pk[i];
    }
    __syncthreads();
    for (unsigned j = tid; j < total; j += 256) {
        unsigned p = stage[j];
        unsigned b = p >> 24;
        unsigned pos = gbase[b] + (j - offx[b]);
        gbuck[(size_t)b * BCAP + pos] = p;
    }
}

// ---------------- bucket scan: exclusive scan of bucket counts ----------------
__global__ __launch_bounds__(256) void k_bscan(const unsigned* __restrict__ gcur, int nbuck,
                                               unsigned* __restrict__ bbase) {
    __shared__ unsigned s[256];
    int tid = threadIdx.x;
    unsigned v = (tid < nbuck) ? gcur[tid] : 0u;
    s[tid] = v;
    __syncthreads();
    for (int off = 1; off < 256; off <<= 1) {
        unsigned t = (tid >= off) ? s[tid - off] : 0u;
        __syncthreads();
        s[tid] += t;
        __syncthreads();
    }
    if (tid < nbuck) bbase[tid] = s[tid] - v;
}

// ---------------- bucket pass 2: fine CSR within each bucket ----------------
__global__ __launch_bounds__(256) void k_finecsr(const unsigned* __restrict__ gcur,
                                                 const unsigned* __restrict__ bbase,
                                                 const unsigned* __restrict__ gbuck,
                                                 unsigned* __restrict__ rowptr,
                                                 ushort* __restrict__ csr16) {
    __shared__ unsigned c[256], sc[256], cur[256];
    int b = blockIdx.x;
    int tid = threadIdx.x;
    unsigned cntL = gcur[b];
    unsigned base = bbase[b];
    const unsigned* gb = gbuck + (size_t)b * BCAP;
    c[tid] = 0;
    __syncthreads();
    for (unsigned j = tid; j < cntL; j += 256) atomicAdd(&c[(gb[j] >> 16) & 255], 1u);
    __syncthreads();
    sc[tid] = c[tid];
    __syncthreads();
    for (int off = 1; off < 256; off <<= 1) {
        unsigned t = (tid >= off) ? sc[tid - off] : 0u;
        __syncthreads();
        sc[tid] += t;
        __syncthreads();
    }
    unsigned ox = sc[tid] - c[tid];
    rowptr[b * 256 + tid] = base + ox;
    cur[tid] = ox;
    __syncthreads();
    for (unsigned j = tid; j < cntL; j += 256) {
        unsigned p = gb[j];
        unsigned dl = (p >> 16) & 255;
        unsigned pos = atomicAdd(&cur[dl], 1u);
        csr16[base + pos] = (ushort)(p & 0xFFFFu);
    }
}

// ---------------- weight pre-transpose + bf16 convert ----------------
__global__ __launch_bounds__(256) void k_w1t(const float* __restrict__ W, bf16_t* __restrict__ Wt) {
    __shared__ float s[16][17];
    int tx = threadIdx.x & 15, ty = threadIdx.x >> 4;
    int kt = blockIdx.x & 31, nt = blockIdx.x >> 5;
    s[ty][tx] = W[(size_t)(kt * 16 + ty) * 128 + nt * 16 + tx];
    __syncthreads();
    Wt[(size_t)(nt * 16 + ty) * 512 + kt * 16 + tx] = (bf16_t)s[tx][ty];
}

__global__ __launch_bounds__(256) void k_wf1t(const float* __restrict__ W, bf16_t* __restrict__ Wt) {
    __shared__ float s[16][17];
    int tx = threadIdx.x & 15, ty = threadIdx.x >> 4;
    int kt = blockIdx.x % 52, nt = blockIdx.x / 52;
    int kg = kt * 16 + ty;
    s[ty][tx] = (kg < 800) ? W[(size_t)kg * 64 + nt * 16 + tx] : 0.f;
    __syncthreads();
    Wt[(size_t)(nt * 16 + ty) * 832 + kt * 16 + tx] = (bf16_t)s[tx][ty];
}

// ---------------- GEMM1 (MFMA): h1bf = bf16(x @ W1) ----------------
__global__ __launch_bounds__(256) void k_gemm1_mfma(const float* __restrict__ x,
                                                    const bf16_t* __restrict__ W1bt,
                                                    bf16_t* __restrict__ h1bf, int n) {
    __shared__ char lds[24576];
    char* As = lds;
    char* Bs = lds + 8192;
    int tid = threadIdx.x;
    int bn = blockIdx.x * 64;
    int wave = tid >> 6, lane = tid & 63;
    int lr = lane & 15, lk = lane >> 4;
    f32x4 acc[8] = {};
    const float4* x4 = (const float4*)x;

    for (int s = 0; s < 8; ++s) {
        int k0 = s * 64;
        #pragma unroll
        for (int i = 0; i < 4; ++i) {
            int v = tid + i * 256;
            int row = v >> 4, c4 = v & 15;
            int node = bn + row;
            float4 val = (node < n) ? x4[(size_t)node * 128 + (k0 >> 2) + c4]
                                    : make_float4(0.f, 0.f, 0.f, 0.f);
            uint off = (uint)(row * 128 + c4 * 8);
            off ^= (uint)((row & 7) << 4);
            *(uint2*)(As + off) = pack4bf16(val);
        }
        #pragma unroll
        for (int i = 0; i < 8; ++i) {
            int v = tid + i * 256;
            int row = v >> 4, c = v & 15;
            uint2 val = *(const uint2*)(W1bt + (size_t)row * 512 + k0 + c * 4);
            uint off = (uint)(row * 128 + c * 8);
            off ^= (uint)((row & 7) << 4);
            *(uint2*)(Bs + off) = val;
        }
        __syncthreads();
        #pragma unroll
        for (int ks = 0; ks < 2; ++ks) {
            uint arow = (uint)(wave * 16 + lr);
            uint aoff = (arow * 128 + (uint)(ks * 64 + lk * 16)) ^ (uint)((lr & 7) << 4);
            bf16x8 av = *(const bf16x8*)(As + aoff);
            #pragma unroll
            for (int f = 0; f < 8; ++f) {
                uint brow = (uint)(f * 16 + lr);
                uint boff = (brow * 128 + (uint)(ks * 64 + lk * 16)) ^ (uint)((lr & 7) << 4);
                bf16x8 bv = *(const bf16x8*)(Bs + boff);
                acc[f] = __builtin_amdgcn_mfma_f32_16x16x32_bf16(av, bv, acc[f], 0, 0, 0);
            }
        }
        __syncthreads();
    }
    #pragma unroll
    for (int f = 0; f < 8; ++f) {
        int nn = f * 16 + lr;
        #pragma unroll
        for (int r = 0; r < 4; ++r) {
            int node = bn + wave * 16 + lk * 4 + r;
            if (node < n) h1bf[(size_t)node * 128 + nn] = (bf16_t)acc[f][r];
        }
    }
}

// ---------------- alpha1 ----------------
__global__ void k_alpha1(const bf16_t* __restrict__ h1bf, const float* __restrict__ a_src,
                         const float* __restrict__ a_dst, float* __restrict__ asrc,
                         float* __restrict__ adst, int n) {
    int idx = blockIdx.x * blockDim.x + threadIdx.x;
    if (idx >= n * 4) return;
    int i = idx >> 2, h = idx & 3;
    const bf16x8* hp = (const bf16x8*)(h1bf + (size_t)i * 128 + h * 32);
    float ss = 0.f, dd = 0.f;
    #pragma unroll
    for (int q = 0; q < 4; ++q) {
        bf16x8 hv = hp[q];
        #pragma unroll
        for (int e = 0; e < 8; ++e) {
            float hf = (float)hv[e];
            ss += hf * a_src[h * 32 + q * 8 + e];
            dd += hf * a_dst[h * 32 + q * 8 + e];
        }
    }
    asrc[idx] = ss;
    adst[idx] = dd;
}

// ---------------- GAT1 aggregation (no-max softmax, bf16 rows, ushort csr) ----------------
__global__ __launch_bounds__(128) void k_gat1(const bf16_t* __restrict__ h1bf,
                                              const float* __restrict__ asrc,
                                              const float* __restrict__ adst,
                                              const float* __restrict__ b1,
                                              const unsigned* __restrict__ rowptr,
                                              const ushort* __restrict__ csr16,
                                              float* __restrict__ h1, int n) {
    int d = blockIdx.x;
    int tid = threadIdx.x;
    int t = tid & 31, h = tid >> 5;
    unsigned k0 = rowptr[d], k1 = rowptr[d + 1];
    float adh = adst[d * 4 + h];
    __shared__ ushort ss[32];
    __shared__ float ps[4 * 32];
    float den = 0.f, acc = 0.f;
    for (unsigned kk = k0; kk < k1; kk += 32) {
        unsigned k = kk + t;
        float p = 0.f;
        ushort s = 0;
        if (k < k1) {
            s = csr16[k];
            float v = asrc[(unsigned)s * 4 + h] + adh;
            v = (v > 0.f) ? v : NEG_SLOPE * v;
            p = __expf(v);
        }
        if (h == 0) ss[t] = s;
        ps[h * 32 + t] = p;
        den += p;
        __syncthreads();
        int nk = (int)min(32u, k1 - kk);
        for (int q = 0; q < nk; ++q) {
            float pq = ps[h * 32 + q];
            acc = fmaf(pq, (float)h1bf[(size_t)ss[q] * 128 + tid], acc);
        }
        __syncthreads();
    }
    #pragma unroll
    for (int m = 16; m >= 1; m >>= 1) den += __shfl_xor(den, m, 32);
    float o = acc / (den + 1e-16f) + b1[tid];
    h1[(size_t)d * 128 + tid] = (o > 0.f) ? o : (__expf(o) - 1.f);
}

// ---------------- h2 = bf16(h1 @ W2) + alpha2 ----------------
__global__ __launch_bounds__(256) void k_h2(const float* __restrict__ h1,
                                            const float* __restrict__ W2,
                                            const float* __restrict__ a_src2,
                                            const float* __restrict__ a_dst2,
                                            bf16_t* __restrict__ h2bf,
                                            float* __restrict__ asrc2,
                                            float* __restrict__ adst2, int n) {
    __shared__ float hs[8 * 128];
    int tid = threadIdx.x;
    int bn = blockIdx.x * 8;
    const float4* h14 = (const float4*)h1;
    float4* hs4 = (float4*)hs;
    {
        int r = tid >> 5, c4 = tid & 31;
        int node = bn + r;
        hs4[tid] = (node < n) ? h14[(size_t)node * 32 + c4] : make_float4(0.f, 0.f, 0.f, 0.f);
    }
    __syncthreads();
    int j = tid & 31, r = tid >> 5;
    float acc = 0.f;
    #pragma unroll 8
    for (int k = 0; k < 128; ++k) {
        acc = fmaf(hs[r * 128 + k], W2[k * 32 + j], acc);
    }
    int node = bn + r;
    float cs = acc * a_src2[j];
    float cd = acc * a_dst2[j];
    #pragma unroll
    for (int m = 16; m >= 1; m >>= 1) {
        cs += __shfl_xor(cs, m, 32);
        cd += __shfl_xor(cd, m, 32);
    }
    if (node < n) {
        h2bf[(size_t)node * 32 + j] = (bf16_t)acc;
        if (j == 0) { asrc2[node] = cs; adst2[node] = cd; }
    }
}

// ---------------- GAT2 aggregation (64 thr, packed bf16 pairs) ----------------
__global__ __launch_bounds__(64) void k_gat2(const bf16_t* __restrict__ h2bf,
                                             const float* __restrict__ asrc2,
                                             const float* __restrict__ adst2,
                                             const float* __restrict__ b2,
                                             const unsigned* __restrict__ rowptr,
                                             const ushort* __restrict__ csr16,
                                             float* __restrict__ g, int n) {
    int d = blockIdx.x;
    int tid = threadIdx.x;
    unsigned k0 = rowptr[d], k1 = rowptr[d + 1];
    float adh = adst2[d];
    const uint* h2u = (const uint*)h2bf;
    __shared__ ushort ss[64];
    __shared__ float ps[64];
    int c = tid & 15, grp = tid >> 4;
    float den = 0.f, acc0 = 0.f, acc1 = 0.f;
    for (unsigned kk = k0; kk < k1; kk += 64) {
        unsigned k = kk + tid;
        float p = 0.f;
        ushort s = 0;
        if (k < k1) {
            s = csr16[k];
            float v = asrc2[s] + adh;
            v = (v > 0.f) ? v : NEG_SLOPE * v;
            p = __expf(v);
        }
        ss[tid] = s;
        ps[tid] = p;
        den += p;
        __syncthreads();
        int nk = (int)min(64u, k1 - kk);
        for (int q = grp; q < nk; q += 4) {
            uint u = h2u[(size_t)ss[q] * 16 + c];
            float pq = ps[q];
            acc0 = fmaf(pq, bflo(u), acc0);
            acc1 = fmaf(pq, bfhi(u), acc1);
        }
        __syncthreads();
    }
    #pragma unroll
    for (int m = 32; m >= 1; m >>= 1) den += __shfl_xor(den, m, 64);
    acc0 += __shfl_xor(acc0, 16, 64);
    acc0 += __shfl_xor(acc0, 32, 64);
    acc1 += __shfl_xor(acc1, 16, 64);
    acc1 += __shfl_xor(acc1, 32, 64);
    if (tid < 16) {
        float inv = 1.f / (den + 1e-16f);
        float2 val;
        val.x = acc0 * inv + b2[2 * tid];
        val.y = acc1 * inv + b2[2 * tid + 1];
        *(float2*)(g + (size_t)d * 32 + 2 * tid) = val;
    }
}

// ---------------- MLP (MFMA): out = relu([txt,g]@Wf1+bf1)@Wf2+bf2 ----------------
__global__ __launch_bounds__(256) void k_mlp_mfma(const float* __restrict__ txt,
                                                  const float* __restrict__ g,
                                                  const bf16_t* __restrict__ Wf1bt,
                                                  const float* __restrict__ bf1,
                                                  const float* __restrict__ Wf2,
                                                  const float* __restrict__ bf2,
                                                  float* __restrict__ out, int n) {
    __shared__ char lds[16384];
    char* As = lds;
    char* Bs = lds + 8192;
    int tid = threadIdx.x;
    int bn = blockIdx.x * 64;
    int wave = tid >> 6, lane = tid & 63;
    int lr = lane & 15, lk = lane >> 4;
    f32x4 acc[4] = {};
    const float4* t4 = (const float4*)txt;
    const float4* g4 = (const float4*)g;

    for (int s = 0; s < 13; ++s) {
        int k0 = s * 64;
        #pragma unroll
        for (int i = 0; i < 4; ++i) {
            int v = tid + i * 256;
            int row = v >> 4, c4 = v & 15;
            int node = bn + row;
            int kg = k0 + c4 * 4;
            float4 val = make_float4(0.f, 0.f, 0.f, 0.f);
            if (node < n) {
                if (kg < 768)      val = t4[(size_t)node * 192 + (kg >> 2)];
                else if (kg < 800) val = g4[(size_t)node * 8 + ((kg - 768) >> 2)];
            }
            uint off = (uint)(row * 128 + c4 * 8);
            off ^= (uint)((row & 7) << 4);
            *(uint2*)(As + off) = pack4bf16(val);
        }
        #pragma unroll
        for (int i = 0; i < 4; ++i) {
            int v = tid + i * 256;
            int row = v >> 4, c = v & 15;
            uint2 val = *(const uint2*)(Wf1bt + (size_t)row * 832 + k0 + c * 4);
            uint off = (uint)(row * 128 + c * 8);
            off ^= (uint)((row & 7) << 4);
            *(uint2*)(Bs + off) = val;
        }
        __syncthreads();
        #pragma unroll
        for (int ks = 0; ks < 2; ++ks) {
            uint arow = (uint)(wave * 16 + lr);
            uint aoff = (arow * 128 + (uint)(ks * 64 + lk * 16)) ^ (uint)((lr & 7) << 4);
            bf16x8 av = *(const bf16x8*)(As + aoff);
            #pragma unroll
            for (int f = 0; f < 4; ++f) {
                uint brow = (uint)(f * 16 + lr);
                uint boff = (brow * 128 + (uint)(ks * 64 + lk * 16)) ^ (uint)((lr & 7) << 4);
                bf16x8 bv = *(const bf16x8*)(Bs + boff);
                acc[f] = __builtin_amdgcn_mfma_f32_16x16x32_bf16(av, bv, acc[f], 0, 0, 0);
            }
        }
        __syncthreads();
    }
    float rsum[4] = {0.f, 0.f, 0.f, 0.f};
    #pragma unroll
    for (int f = 0; f < 4; ++f) {
        int nn = f * 16 + lr;
        float bb = bf1[nn], ww = Wf2[nn];
        #pragma unroll
        for (int r = 0; r < 4; ++r) {
            float v = acc[f][r] + bb;
            rsum[r] += fmaxf(v, 0.f) * ww;
        }
    }
    #pragma unroll
    for (int r = 0; r < 4; ++r) {
        #pragma unroll
        for (int m = 8; m >= 1; m >>= 1) rsum[r] += __shfl_xor(rsum[r], m, 64);
        if (lr == 0) {
            int node = bn + wave * 16 + lk * 4 + r;
            if (node < n) out[node] = rsum[r] + bf2[0];
        }
    }
}

extern "C" void kernel_launch(void* const* d_in, const int* in_sizes, int n_in,
                              void* d_out, int out_size, void* d_ws, size_t ws_size,
                              hipStream_t stream) {
    const float* txt    = (const float*)d_in[0];
    const float* x      = (const float*)d_in[1];
    const float* W1     = (const float*)d_in[2];
    const float* a_src1 = (const float*)d_in[3];
    const float* a_dst1 = (const float*)d_in[4];
    const float* b1     = (const float*)d_in[5];
    const float* W2     = (const float*)d_in[6];
    const float* a_src2 = (const float*)d_in[7];
    const float* a_dst2 = (const float*)d_in[8];
    const float* b2     = (const float*)d_in[9];
    const float* Wf1    = (const float*)d_in[10];
    const float* bf1    = (const float*)d_in[11];
    const float* Wf2    = (const float*)d_in[12];
    const float* bf2    = (const float*)d_in[13];
    const int*   ei     = (const int*)d_in[14];

    int n  = in_sizes[1] / 512;
    int E  = in_sizes[14] / 2;
    int ET = E + n;
    int nbuck = (n + 255) >> 8;
    float* out = (float*)d_out;

    char* p = (char*)d_ws;
    auto alloc = [&](size_t bytes) -> char* {
        char* q = p;
        p += (bytes + 255) & ~(size_t)255;
        return q;
    };
    bf16_t*   h1bf   = (bf16_t*)alloc((size_t)n * 128 * 2);
    float*    h1     = (float*)alloc((size_t)n * 128 * 4);
    float*    asrc1  = (float*)alloc((size_t)n * 4 * 4);
    float*    adst1  = (float*)alloc((size_t)n * 4 * 4);
    bf16_t*   h2bf   = (bf16_t*)alloc((size_t)n * 32 * 2);
    float*    asrc2  = (float*)alloc((size_t)n * 4);
    float*    adst2  = (float*)alloc((size_t)n * 4);
    float*    gbuf   = (float*)alloc((size_t)n * 32 * 4);
    unsigned* rowptr = (unsigned*)alloc((size_t)(nbuck * 256 + 1) * 4);
    ushort*   csr16  = (ushort*)alloc((size_t)ET * 2);
    unsigned* gbuck  = (unsigned*)alloc((size_t)nbuck * BCAP * 4);
    unsigned* gcur   = (unsigned*)alloc((size_t)nbuck * 4);
    unsigned* bbase  = (unsigned*)alloc((size_t)nbuck * 4);
    bf16_t*   W1bt   = (bf16_t*)alloc((size_t)128 * 512 * 2);
    bf16_t*   Wf1bt  = (bf16_t*)alloc((size_t)64 * 832 * 2);

    hipMemsetAsync(gcur, 0, (size_t)nbuck * 4, stream);

    k_w1t<<<256, 256, 0, stream>>>(W1, W1bt);
    k_wf1t<<<208, 256, 0, stream>>>(Wf1, Wf1bt);

    int ntiles = (ET + 4095) / 4096;
    k_bucket<<<ntiles, 256, 0, stream>>>(ei, E, n, nbuck, gcur, gbuck);
    k_bscan<<<1, 256, 0, stream>>>(gcur, nbuck, bbase);
    k_finecsr<<<nbuck, 256, 0, stream>>>(gcur, bbase, gbuck, rowptr, csr16);

    int nb64 = (n + 63) / 64;
    k_gemm1_mfma<<<nb64, 256, 0, stream>>>(x, W1bt, h1bf, n);
    k_alpha1<<<(n * 4 + 255) / 256, 256, 0, stream>>>(h1bf, a_src1, a_dst1, asrc1, adst1, n);
    k_gat1<<<n, 128, 0, stream>>>(h1bf, asrc1, adst1, b1, rowptr, csr16, h1, n);
    k_h2<<<(n + 7) / 8, 256, 0, stream>>>(h1, W2, a_src2, a_dst2, h2bf, asrc2, adst2, n);
    k_gat2<<<n, 64, 0, stream>>>(h2bf, asrc2, adst2, b2, rowptr, csr16, gbuf, n);
    k_mlp_mfma<<<nb64, 256, 0, stream>>>(txt, gbuf, Wf1bt, bf1, Wf2, bf2, out, n);
}

// Round 4
// 276.839 us; speedup vs baseline: 2.5748x; 1.0608x over previous
//
#include <hip/hip_runtime.h>
#include <hip/hip_bf16.h>
#include <cstdint>

#define NEG_SLOPE 0.2f
#define BCAP 16384

typedef __bf16 bf16_t;
typedef __bf16 bf16x8 __attribute__((ext_vector_type(8)));
typedef float f32x4 __attribute__((ext_vector_type(4)));

__device__ __forceinline__ uint2 pack4bf16(float4 v) {
    ushort u0 = __builtin_bit_cast(ushort, (bf16_t)v.x);
    ushort u1 = __builtin_bit_cast(ushort, (bf16_t)v.y);
    ushort u2 = __builtin_bit_cast(ushort, (bf16_t)v.z);
    ushort u3 = __builtin_bit_cast(ushort, (bf16_t)v.w);
    uint2 r;
    r.x = (uint)u0 | ((uint)u1 << 16);
    r.y = (uint)u2 | ((uint)u3 << 16);
    return r;
}

__device__ __forceinline__ float bflo(uint u) { return __builtin_bit_cast(float, u << 16); }
__device__ __forceinline__ float bfhi(uint u) { return __builtin_bit_cast(float, u & 0xFFFF0000u); }

// ---------------- bucket pass 1: group edges by dst>>8 into per-bucket regions ----------------
__global__ __launch_bounds__(256) void k_bucket(const int* __restrict__ ei, int E, int n,
                                                int nbuck, unsigned* __restrict__ gcur,
                                                unsigned* __restrict__ gbuck) {
    __shared__ unsigned stage[4096];
    __shared__ unsigned cnt[256], sc[256], offx[256], gbase[256];
    int tid = threadIdx.x;
    int ET = E + n;
    int tileStart = blockIdx.x * 4096;
    cnt[tid] = 0;
    __syncthreads();
    unsigned pk[16];
    int rk[16];
    #pragma unroll
    for (int i = 0; i < 16; ++i) {
        int idx = tileStart + i * 256 + tid;
        rk[i] = -1;
        if (idx < ET) {
            int s, d;
            if (idx < E) { s = ei[idx]; d = ei[E + idx]; } else { s = d = idx - E; }
            pk[i] = ((unsigned)d << 16) | (unsigned)s;
            rk[i] = (int)atomicAdd(&cnt[(unsigned)d >> 8], 1u);
        }
    }
    __syncthreads();
    sc[tid] = cnt[tid];
    __syncthreads();
    for (int off = 1; off < 256; off <<= 1) {
        unsigned t = (tid >= off) ? sc[tid - off] : 0u;
        __syncthreads();
        sc[tid] += t;
        __syncthreads();
    }
    offx[tid] = sc[tid] - cnt[tid];
    if (tid < nbuck && cnt[tid] > 0) gbase[tid] = atomicAdd(&gcur[tid], cnt[tid]);
    unsigned total = sc[255];
    __syncthreads();
    #pragma unroll
    for (int i = 0; i < 16; ++i) {
        if (rk[i] >= 0) stage[offx[pk[i] >> 24] + rk[i]] = pk[i];
    }
    __syncthreads();
    for (unsigned j = tid; j < total; j += 256) {
        unsigned p = stage[j];
        unsigned b = p >> 24;
        unsigned pos = gbase[b] + (j - offx[b]);
        gbuck[(size_t)b * BCAP + pos] = p;
    }
}

// ---------------- bucket pass 2: fine CSR within each bucket (self-scans bucket counts) ----------------
__global__ __launch_bounds__(256) void k_finecsr(const unsigned* __restrict__ gcur,
                                                 const unsigned* __restrict__ gbuck,
                                                 int nbuck,
                                                 unsigned* __restrict__ rowptr,
                                                 ushort* __restrict__ csr16) {
    __shared__ unsigned s[256];
    __shared__ unsigned c[256], sc[256], cur[256];
    int b = blockIdx.x;
    int tid = threadIdx.x;
    // scan all bucket counts to find this bucket's global base
    unsigned v = (tid < nbuck) ? gcur[tid] : 0u;
    s[tid] = v;
    __syncthreads();
    for (int off = 1; off < 256; off <<= 1) {
        unsigned t = (tid >= off) ? s[tid - off] : 0u;
        __syncthreads();
        s[tid] += t;
        __syncthreads();
    }
    unsigned base = s[b] - gcur[b];   // exclusive prefix at b
    unsigned cntL = gcur[b];
    const unsigned* gb = gbuck + (size_t)b * BCAP;
    c[tid] = 0;
    __syncthreads();
    for (unsigned j = tid; j < cntL; j += 256) atomicAdd(&c[(gb[j] >> 16) & 255], 1u);
    __syncthreads();
    sc[tid] = c[tid];
    __syncthreads();
    for (int off = 1; off < 256; off <<= 1) {
        unsigned t = (tid >= off) ? sc[tid - off] : 0u;
        __syncthreads();
        sc[tid] += t;
        __syncthreads();
    }
    unsigned ox = sc[tid] - c[tid];
    rowptr[b * 256 + tid] = base + ox;
    cur[tid] = ox;
    __syncthreads();
    for (unsigned j = tid; j < cntL; j += 256) {
        unsigned p = gb[j];
        unsigned dl = (p >> 16) & 255;
        unsigned pos = atomicAdd(&cur[dl], 1u);
        csr16[base + pos] = (ushort)(p & 0xFFFFu);
    }
}

// ---------------- weight pre-transpose + bf16 convert ----------------
__global__ __launch_bounds__(256) void k_w1t(const float* __restrict__ W, bf16_t* __restrict__ Wt) {
    __shared__ float s[16][17];
    int tx = threadIdx.x & 15, ty = threadIdx.x >> 4;
    int kt = blockIdx.x & 31, nt = blockIdx.x >> 5;
    s[ty][tx] = W[(size_t)(kt * 16 + ty) * 128 + nt * 16 + tx];
    __syncthreads();
    Wt[(size_t)(nt * 16 + ty) * 512 + kt * 16 + tx] = (bf16_t)s[tx][ty];
}

__global__ __launch_bounds__(256) void k_wf1t(const float* __restrict__ W, bf16_t* __restrict__ Wt) {
    __shared__ float s[16][17];
    int tx = threadIdx.x & 15, ty = threadIdx.x >> 4;
    int kt = blockIdx.x % 52, nt = blockIdx.x / 52;
    int kg = kt * 16 + ty;
    s[ty][tx] = (kg < 800) ? W[(size_t)kg * 64 + nt * 16 + tx] : 0.f;
    __syncthreads();
    Wt[(size_t)(nt * 16 + ty) * 832 + kt * 16 + tx] = (bf16_t)s[tx][ty];
}

// ---------------- GEMM1 (MFMA) + fused alpha1 ----------------
// h1bf = bf16(x @ W1); asrc/adst[(node,h)] = dot(h1_row_head, a_src/a_dst) from f32 acc
__global__ __launch_bounds__(256) void k_gemm1_mfma(const float* __restrict__ x,
                                                    const bf16_t* __restrict__ W1bt,
                                                    const float* __restrict__ a_src1,
                                                    const float* __restrict__ a_dst1,
                                                    bf16_t* __restrict__ h1bf,
                                                    float* __restrict__ asrc,
                                                    float* __restrict__ adst, int n) {
    __shared__ char lds[24576];
    char* As = lds;
    char* Bs = lds + 8192;
    int tid = threadIdx.x;
    int bn = blockIdx.x * 64;
    int wave = tid >> 6, lane = tid & 63;
    int lr = lane & 15, lk = lane >> 4;
    f32x4 acc[8] = {};
    const float4* x4 = (const float4*)x;

    for (int s = 0; s < 8; ++s) {
        int k0 = s * 64;
        #pragma unroll
        for (int i = 0; i < 4; ++i) {
            int v = tid + i * 256;
            int row = v >> 4, c4 = v & 15;
            int node = bn + row;
            float4 val = (node < n) ? x4[(size_t)node * 128 + (k0 >> 2) + c4]
                                    : make_float4(0.f, 0.f, 0.f, 0.f);
            uint off = (uint)(row * 128 + c4 * 8);
            off ^= (uint)((row & 7) << 4);
            *(uint2*)(As + off) = pack4bf16(val);
        }
        #pragma unroll
        for (int i = 0; i < 8; ++i) {
            int v = tid + i * 256;
            int row = v >> 4, c = v & 15;
            uint2 val = *(const uint2*)(W1bt + (size_t)row * 512 + k0 + c * 4);
            uint off = (uint)(row * 128 + c * 8);
            off ^= (uint)((row & 7) << 4);
            *(uint2*)(Bs + off) = val;
        }
        __syncthreads();
        #pragma unroll
        for (int ks = 0; ks < 2; ++ks) {
            uint arow = (uint)(wave * 16 + lr);
            uint aoff = (arow * 128 + (uint)(ks * 64 + lk * 16)) ^ (uint)((lr & 7) << 4);
            bf16x8 av = *(const bf16x8*)(As + aoff);
            #pragma unroll
            for (int f = 0; f < 8; ++f) {
                uint brow = (uint)(f * 16 + lr);
                uint boff = (brow * 128 + (uint)(ks * 64 + lk * 16)) ^ (uint)((lr & 7) << 4);
                bf16x8 bv = *(const bf16x8*)(Bs + boff);
                acc[f] = __builtin_amdgcn_mfma_f32_16x16x32_bf16(av, bv, acc[f], 0, 0, 0);
            }
        }
        __syncthreads();
    }
    // C store: col = f*16+lr, row(node) = wave*16 + lk*4 + r
    #pragma unroll
    for (int f = 0; f < 8; ++f) {
        int nn = f * 16 + lr;
        #pragma unroll
        for (int r = 0; r < 4; ++r) {
            int node = bn + wave * 16 + lk * 4 + r;
            if (node < n) h1bf[(size_t)node * 128 + nn] = (bf16_t)acc[f][r];
        }
    }
    // fused alpha1: head h <- fragments {2h, 2h+1}; within-head col = (f&1)*16 + lr
    float asv[8], adv[8];
    #pragma unroll
    for (int h = 0; h < 4; ++h) {
        asv[2 * h]     = a_src1[h * 32 + lr];
        asv[2 * h + 1] = a_src1[h * 32 + 16 + lr];
        adv[2 * h]     = a_dst1[h * 32 + lr];
        adv[2 * h + 1] = a_dst1[h * 32 + 16 + lr];
    }
    #pragma unroll
    for (int r = 0; r < 4; ++r) {
        int node = bn + wave * 16 + lk * 4 + r;
        #pragma unroll
        for (int h = 0; h < 4; ++h) {
            float ps = acc[2 * h][r] * asv[2 * h] + acc[2 * h + 1][r] * asv[2 * h + 1];
            float pd = acc[2 * h][r] * adv[2 * h] + acc[2 * h + 1][r] * adv[2 * h + 1];
            #pragma unroll
            for (int m = 8; m >= 1; m >>= 1) {
                ps += __shfl_xor(ps, m, 64);
                pd += __shfl_xor(pd, m, 64);
            }
            if (node < n) {
                if (lr == h)     asrc[node * 4 + h] = ps;
                if (lr == h + 4) adst[node * 4 + h] = pd;
            }
        }
    }
}

// ---------------- GAT1 aggregation + fused h2/alpha2 ----------------
// per dst node: softmax-aggregate h1bf -> o (ELU'd), then h2 = o @ W2 and alpha2 dots.
__global__ __launch_bounds__(128) void k_gat1(const bf16_t* __restrict__ h1bf,
                                              const float* __restrict__ asrc,
                                              const float* __restrict__ adst,
                                              const float* __restrict__ b1,
                                              const unsigned* __restrict__ rowptr,
                                              const ushort* __restrict__ csr16,
                                              const float* __restrict__ W2,
                                              const float* __restrict__ a_src2,
                                              const float* __restrict__ a_dst2,
                                              bf16_t* __restrict__ h2bf,
                                              float* __restrict__ asrc2,
                                              float* __restrict__ adst2, int n) {
    int d = blockIdx.x;
    int tid = threadIdx.x;
    int t = tid & 31, h = tid >> 5;
    unsigned k0 = rowptr[d], k1 = rowptr[d + 1];
    float adh = adst[d * 4 + h];
    __shared__ ushort ss[32];
    __shared__ float ps[4 * 32];
    __shared__ float os[128];
    __shared__ float ps2[128];
    float den = 0.f, acc = 0.f;
    for (unsigned kk = k0; kk < k1; kk += 32) {
        unsigned k = kk + t;
        float p = 0.f;
        ushort s = 0;
        if (k < k1) {
            s = csr16[k];
            float v = asrc[(unsigned)s * 4 + h] + adh;
            v = (v > 0.f) ? v : NEG_SLOPE * v;
            p = __expf(v);
        }
        if (h == 0) ss[t] = s;
        ps[h * 32 + t] = p;
        den += p;
        __syncthreads();
        int nk = (int)min(32u, k1 - kk);
        for (int q = 0; q < nk; ++q) {
            float pq = ps[h * 32 + q];
            acc = fmaf(pq, (float)h1bf[(size_t)ss[q] * 128 + tid], acc);
        }
        __syncthreads();
    }
    #pragma unroll
    for (int m = 16; m >= 1; m >>= 1) den += __shfl_xor(den, m, 32);
    float o = acc / (den + 1e-16f) + b1[tid];
    o = (o > 0.f) ? o : (__expf(o) - 1.f);   // ELU
    // fused h2 = o @ W2 [128x32]
    os[tid] = o;
    __syncthreads();
    int j = tid & 31, kc = tid >> 5;
    float part = 0.f;
    #pragma unroll
    for (int i = 0; i < 32; ++i) {
        int k = kc * 32 + i;
        part = fmaf(os[k], W2[k * 32 + j], part);
    }
    ps2[kc * 32 + j] = part;
    __syncthreads();
    if (tid < 32) {
        float h2v = ps2[tid] + ps2[32 + tid] + ps2[64 + tid] + ps2[96 + tid];
        float cs = h2v * a_src2[tid];
        float cd = h2v * a_dst2[tid];
        #pragma unroll
        for (int m = 16; m >= 1; m >>= 1) {
            cs += __shfl_xor(cs, m, 64);
            cd += __shfl_xor(cd, m, 64);
        }
        h2bf[(size_t)d * 32 + tid] = (bf16_t)h2v;
        if (tid == 0) { asrc2[d] = cs; adst2[d] = cd; }
    }
}

// ---------------- GAT2 aggregation (64 thr, packed bf16 pairs) ----------------
__global__ __launch_bounds__(64) void k_gat2(const bf16_t* __restrict__ h2bf,
                                             const float* __restrict__ asrc2,
                                             const float* __restrict__ adst2,
                                             const float* __restrict__ b2,
                                             const unsigned* __restrict__ rowptr,
                                             const ushort* __restrict__ csr16,
                                             float* __restrict__ g, int n) {
    int d = blockIdx.x;
    int tid = threadIdx.x;
    unsigned k0 = rowptr[d], k1 = rowptr[d + 1];
    float adh = adst2[d];
    const uint* h2u = (const uint*)h2bf;
    __shared__ ushort ss[64];
    __shared__ float ps[64];
    int c = tid & 15, grp = tid >> 4;
    float den = 0.f, acc0 = 0.f, acc1 = 0.f;
    for (unsigned kk = k0; kk < k1; kk += 64) {
        unsigned k = kk + tid;
        float p = 0.f;
        ushort s = 0;
        if (k < k1) {
            s = csr16[k];
            float v = asrc2[s] + adh;
            v = (v > 0.f) ? v : NEG_SLOPE * v;
            p = __expf(v);
        }
        ss[tid] = s;
        ps[tid] = p;
        den += p;
        __syncthreads();
        int nk = (int)min(64u, k1 - kk);
        for (int q = grp; q < nk; q += 4) {
            uint u = h2u[(size_t)ss[q] * 16 + c];
            float pq = ps[q];
            acc0 = fmaf(pq, bflo(u), acc0);
            acc1 = fmaf(pq, bfhi(u), acc1);
        }
        __syncthreads();
    }
    #pragma unroll
    for (int m = 32; m >= 1; m >>= 1) den += __shfl_xor(den, m, 64);
    acc0 += __shfl_xor(acc0, 16, 64);
    acc0 += __shfl_xor(acc0, 32, 64);
    acc1 += __shfl_xor(acc1, 16, 64);
    acc1 += __shfl_xor(acc1, 32, 64);
    if (tid < 16) {
        float inv = 1.f / (den + 1e-16f);
        float2 val;
        val.x = acc0 * inv + b2[2 * tid];
        val.y = acc1 * inv + b2[2 * tid + 1];
        *(float2*)(g + (size_t)d * 32 + 2 * tid) = val;
    }
}

// ---------------- MLP (MFMA): out = relu([txt,g]@Wf1+bf1)@Wf2+bf2 ----------------
__global__ __launch_bounds__(256) void k_mlp_mfma(const float* __restrict__ txt,
                                                  const float* __restrict__ g,
                                                  const bf16_t* __restrict__ Wf1bt,
                                                  const float* __restrict__ bf1,
                                                  const float* __restrict__ Wf2,
                                                  const float* __restrict__ bf2,
                                                  float* __restrict__ out, int n) {
    __shared__ char lds[16384];
    char* As = lds;
    char* Bs = lds + 8192;
    int tid = threadIdx.x;
    int bn = blockIdx.x * 64;
    int wave = tid >> 6, lane = tid & 63;
    int lr = lane & 15, lk = lane >> 4;
    f32x4 acc[4] = {};
    const float4* t4 = (const float4*)txt;
    const float4* g4 = (const float4*)g;

    for (int s = 0; s < 13; ++s) {
        int k0 = s * 64;
        #pragma unroll
        for (int i = 0; i < 4; ++i) {
            int v = tid + i * 256;
            int row = v >> 4, c4 = v & 15;
            int node = bn + row;
            int kg = k0 + c4 * 4;
            float4 val = make_float4(0.f, 0.f, 0.f, 0.f);
            if (node < n) {
                if (kg < 768)      val = t4[(size_t)node * 192 + (kg >> 2)];
                else if (kg < 800) val = g4[(size_t)node * 8 + ((kg - 768) >> 2)];
            }
            uint off = (uint)(row * 128 + c4 * 8);
            off ^= (uint)((row & 7) << 4);
            *(uint2*)(As + off) = pack4bf16(val);
        }
        #pragma unroll
        for (int i = 0; i < 4; ++i) {
            int v = tid + i * 256;
            int row = v >> 4, c = v & 15;
            uint2 val = *(const uint2*)(Wf1bt + (size_t)row * 832 + k0 + c * 4);
            uint off = (uint)(row * 128 + c * 8);
            off ^= (uint)((row & 7) << 4);
            *(uint2*)(Bs + off) = val;
        }
        __syncthreads();
        #pragma unroll
        for (int ks = 0; ks < 2; ++ks) {
            uint arow = (uint)(wave * 16 + lr);
            uint aoff = (arow * 128 + (uint)(ks * 64 + lk * 16)) ^ (uint)((lr & 7) << 4);
            bf16x8 av = *(const bf16x8*)(As + aoff);
            #pragma unroll
            for (int f = 0; f < 4; ++f) {
                uint brow = (uint)(f * 16 + lr);
                uint boff = (brow * 128 + (uint)(ks * 64 + lk * 16)) ^ (uint)((lr & 7) << 4);
                bf16x8 bv = *(const bf16x8*)(Bs + boff);
                acc[f] = __builtin_amdgcn_mfma_f32_16x16x32_bf16(av, bv, acc[f], 0, 0, 0);
            }
        }
        __syncthreads();
    }
    float rsum[4] = {0.f, 0.f, 0.f, 0.f};
    #pragma unroll
    for (int f = 0; f < 4; ++f) {
        int nn = f * 16 + lr;
        float bb = bf1[nn], ww = Wf2[nn];
        #pragma unroll
        for (int r = 0; r < 4; ++r) {
            float v = acc[f][r] + bb;
            rsum[r] += fmaxf(v, 0.f) * ww;
        }
    }
    #pragma unroll
    for (int r = 0; r < 4; ++r) {
        #pragma unroll
        for (int m = 8; m >= 1; m >>= 1) rsum[r] += __shfl_xor(rsum[r], m, 64);
        if (lr == 0) {
            int node = bn + wave * 16 + lk * 4 + r;
            if (node < n) out[node] = rsum[r] + bf2[0];
        }
    }
}

extern "C" void kernel_launch(void* const* d_in, const int* in_sizes, int n_in,
                              void* d_out, int out_size, void* d_ws, size_t ws_size,
                              hipStream_t stream) {
    const float* txt    = (const float*)d_in[0];
    const float* x      = (const float*)d_in[1];
    const float* W1     = (const float*)d_in[2];
    const float* a_src1 = (const float*)d_in[3];
    const float* a_dst1 = (const float*)d_in[4];
    const float* b1     = (const float*)d_in[5];
    const float* W2     = (const float*)d_in[6];
    const float* a_src2 = (const float*)d_in[7];
    const float* a_dst2 = (const float*)d_in[8];
    const float* b2     = (const float*)d_in[9];
    const float* Wf1    = (const float*)d_in[10];
    const float* bf1    = (const float*)d_in[11];
    const float* Wf2    = (const float*)d_in[12];
    const float* bf2    = (const float*)d_in[13];
    const int*   ei     = (const int*)d_in[14];

    int n  = in_sizes[1] / 512;
    int E  = in_sizes[14] / 2;
    int ET = E + n;
    int nbuck = (n + 255) >> 8;
    float* out = (float*)d_out;

    char* p = (char*)d_ws;
    auto alloc = [&](size_t bytes) -> char* {
        char* q = p;
        p += (bytes + 255) & ~(size_t)255;
        return q;
    };
    bf16_t*   h1bf   = (bf16_t*)alloc((size_t)n * 128 * 2);
    float*    asrc1  = (float*)alloc((size_t)n * 4 * 4);
    float*    adst1  = (float*)alloc((size_t)n * 4 * 4);
    bf16_t*   h2bf   = (bf16_t*)alloc((size_t)n * 32 * 2);
    float*    asrc2  = (float*)alloc((size_t)n * 4);
    float*    adst2  = (float*)alloc((size_t)n * 4);
    float*    gbuf   = (float*)alloc((size_t)n * 32 * 4);
    unsigned* rowptr = (unsigned*)alloc((size_t)(nbuck * 256 + 1) * 4);
    ushort*   csr16  = (ushort*)alloc((size_t)ET * 2);
    unsigned* gbuck  = (unsigned*)alloc((size_t)nbuck * BCAP * 4);
    unsigned* gcur   = (unsigned*)alloc((size_t)nbuck * 4);
    bf16_t*   W1bt   = (bf16_t*)alloc((size_t)128 * 512 * 2);
    bf16_t*   Wf1bt  = (bf16_t*)alloc((size_t)64 * 832 * 2);

    hipMemsetAsync(gcur, 0, (size_t)nbuck * 4, stream);

    k_w1t<<<256, 256, 0, stream>>>(W1, W1bt);
    k_wf1t<<<208, 256, 0, stream>>>(Wf1, Wf1bt);

    int ntiles = (ET + 4095) / 4096;
    k_bucket<<<ntiles, 256, 0, stream>>>(ei, E, n, nbuck, gcur, gbuck);
    k_finecsr<<<nbuck, 256, 0, stream>>>(gcur, gbuck, nbuck, rowptr, csr16);

    int nb64 = (n + 63) / 64;
    k_gemm1_mfma<<<nb64, 256, 0, stream>>>(x, W1bt, a_src1, a_dst1, h1bf, asrc1, adst1, n);
    k_gat1<<<n, 128, 0, stream>>>(h1bf, asrc1, adst1, b1, rowptr, csr16,
                                  W2, a_src2, a_dst2, h2bf, asrc2, adst2, n);
    k_gat2<<<n, 64, 0, stream>>>(h2bf, asrc2, adst2, b2, rowptr, csr16, gbuf, n);
    k_mlp_mfma<<<nb64, 256, 0, stream>>>(txt, gbuf, Wf1bt, bf1, Wf2, bf2, out, n);
}

// Round 5
// 272.790 us; speedup vs baseline: 2.6131x; 1.0148x over previous
//
#include <hip/hip_runtime.h>
#include <hip/hip_bf16.h>
#include <cstdint>

#define NEG_SLOPE 0.2f
#define BCAP 16384

typedef __bf16 bf16_t;
typedef __bf16 bf16x8 __attribute__((ext_vector_type(8)));
typedef float f32x4 __attribute__((ext_vector_type(4)));

__device__ __forceinline__ uint2 pack4bf16(float4 v) {
    ushort u0 = __builtin_bit_cast(ushort, (bf16_t)v.x);
    ushort u1 = __builtin_bit_cast(ushort, (bf16_t)v.y);
    ushort u2 = __builtin_bit_cast(ushort, (bf16_t)v.z);
    ushort u3 = __builtin_bit_cast(ushort, (bf16_t)v.w);
    uint2 r;
    r.x = (uint)u0 | ((uint)u1 << 16);
    r.y = (uint)u2 | ((uint)u3 << 16);
    return r;
}

__device__ __forceinline__ float bflo(uint u) { return __builtin_bit_cast(float, u << 16); }
__device__ __forceinline__ float bfhi(uint u) { return __builtin_bit_cast(float, u & 0xFFFF0000u); }

// ---------------- bucket pass 1: group edges by dst>>8 into per-bucket regions ----------------
__global__ __launch_bounds__(256) void k_bucket(const int* __restrict__ ei, int E, int n,
                                                int nbuck, unsigned* __restrict__ gcur,
                                                unsigned* __restrict__ gbuck) {
    __shared__ unsigned stage[4096];
    __shared__ unsigned cnt[256], sc[256], offx[256], gbase[256];
    int tid = threadIdx.x;
    int ET = E + n;
    int tileStart = blockIdx.x * 4096;
    cnt[tid] = 0;
    __syncthreads();
    unsigned pk[16];
    int rk[16];
    #pragma unroll
    for (int i = 0; i < 16; ++i) {
        int idx = tileStart + i * 256 + tid;
        rk[i] = -1;
        if (idx < ET) {
            int s, d;
            if (idx < E) { s = ei[idx]; d = ei[E + idx]; } else { s = d = idx - E; }
            pk[i] = ((unsigned)d << 16) | (unsigned)s;
            rk[i] = (int)atomicAdd(&cnt[(unsigned)d >> 8], 1u);
        }
    }
    __syncthreads();
    sc[tid] = cnt[tid];
    __syncthreads();
    for (int off = 1; off < 256; off <<= 1) {
        unsigned t = (tid >= off) ? sc[tid - off] : 0u;
        __syncthreads();
        sc[tid] += t;
        __syncthreads();
    }
    offx[tid] = sc[tid] - cnt[tid];
    if (tid < nbuck && cnt[tid] > 0) gbase[tid] = atomicAdd(&gcur[tid], cnt[tid]);
    unsigned total = sc[255];
    __syncthreads();
    #pragma unroll
    for (int i = 0; i < 16; ++i) {
        if (rk[i] >= 0) stage[offx[pk[i] >> 24] + rk[i]] = pk[i];
    }
    __syncthreads();
    for (unsigned j = tid; j < total; j += 256) {
        unsigned p = stage[j];
        unsigned b = p >> 24;
        unsigned pos = gbase[b] + (j - offx[b]);
        gbuck[(size_t)b * BCAP + pos] = p;
    }
}

// ---------------- bucket pass 2: fine CSR within each bucket (self-scans bucket counts) ----------------
__global__ __launch_bounds__(256) void k_finecsr(const unsigned* __restrict__ gcur,
                                                 const unsigned* __restrict__ gbuck,
                                                 int nbuck,
                                                 unsigned* __restrict__ rowptr,
                                                 ushort* __restrict__ csr16) {
    __shared__ unsigned s[256];
    __shared__ unsigned c[256], sc[256], cur[256];
    int b = blockIdx.x;
    int tid = threadIdx.x;
    unsigned v = (tid < nbuck) ? gcur[tid] : 0u;
    s[tid] = v;
    __syncthreads();
    for (int off = 1; off < 256; off <<= 1) {
        unsigned t = (tid >= off) ? s[tid - off] : 0u;
        __syncthreads();
        s[tid] += t;
        __syncthreads();
    }
    unsigned base = s[b] - gcur[b];
    unsigned cntL = gcur[b];
    const unsigned* gb = gbuck + (size_t)b * BCAP;
    c[tid] = 0;
    __syncthreads();
    for (unsigned j = tid; j < cntL; j += 256) atomicAdd(&c[(gb[j] >> 16) & 255], 1u);
    __syncthreads();
    sc[tid] = c[tid];
    __syncthreads();
    for (int off = 1; off < 256; off <<= 1) {
        unsigned t = (tid >= off) ? sc[tid - off] : 0u;
        __syncthreads();
        sc[tid] += t;
        __syncthreads();
    }
    unsigned ox = sc[tid] - c[tid];
    rowptr[b * 256 + tid] = base + ox;
    cur[tid] = ox;
    __syncthreads();
    for (unsigned j = tid; j < cntL; j += 256) {
        unsigned p = gb[j];
        unsigned dl = (p >> 16) & 255;
        unsigned pos = atomicAdd(&cur[dl], 1u);
        csr16[base + pos] = (ushort)(p & 0xFFFFu);
    }
}

// ---------------- weight pre-transpose + bf16 convert ----------------
__global__ __launch_bounds__(256) void k_w1t(const float* __restrict__ W, bf16_t* __restrict__ Wt) {
    __shared__ float s[16][17];
    int tx = threadIdx.x & 15, ty = threadIdx.x >> 4;
    int kt = blockIdx.x & 31, nt = blockIdx.x >> 5;
    s[ty][tx] = W[(size_t)(kt * 16 + ty) * 128 + nt * 16 + tx];
    __syncthreads();
    Wt[(size_t)(nt * 16 + ty) * 512 + kt * 16 + tx] = (bf16_t)s[tx][ty];
}

__global__ __launch_bounds__(256) void k_wf1t(const float* __restrict__ W, bf16_t* __restrict__ Wt) {
    __shared__ float s[16][17];
    int tx = threadIdx.x & 15, ty = threadIdx.x >> 4;
    int kt = blockIdx.x % 52, nt = blockIdx.x / 52;
    int kg = kt * 16 + ty;
    s[ty][tx] = (kg < 800) ? W[(size_t)kg * 64 + nt * 16 + tx] : 0.f;
    __syncthreads();
    Wt[(size_t)(nt * 16 + ty) * 832 + kt * 16 + tx] = (bf16_t)s[tx][ty];
}

// ---------------- GEMM1 (MFMA) + fused alpha1 ----------------
__global__ __launch_bounds__(256) void k_gemm1_mfma(const float* __restrict__ x,
                                                    const bf16_t* __restrict__ W1bt,
                                                    const float* __restrict__ a_src1,
                                                    const float* __restrict__ a_dst1,
                                                    bf16_t* __restrict__ h1bf,
                                                    float* __restrict__ asrc,
                                                    float* __restrict__ adst, int n) {
    __shared__ char lds[24576];
    char* As = lds;
    char* Bs = lds + 8192;
    int tid = threadIdx.x;
    int bn = blockIdx.x * 64;
    int wave = tid >> 6, lane = tid & 63;
    int lr = lane & 15, lk = lane >> 4;
    f32x4 acc[8] = {};
    const float4* x4 = (const float4*)x;

    for (int s = 0; s < 8; ++s) {
        int k0 = s * 64;
        #pragma unroll
        for (int i = 0; i < 4; ++i) {
            int v = tid + i * 256;
            int row = v >> 4, c4 = v & 15;
            int node = bn + row;
            float4 val = (node < n) ? x4[(size_t)node * 128 + (k0 >> 2) + c4]
                                    : make_float4(0.f, 0.f, 0.f, 0.f);
            uint off = (uint)(row * 128 + c4 * 8);
            off ^= (uint)((row & 7) << 4);
            *(uint2*)(As + off) = pack4bf16(val);
        }
        #pragma unroll
        for (int i = 0; i < 8; ++i) {
            int v = tid + i * 256;
            int row = v >> 4, c = v & 15;
            uint2 val = *(const uint2*)(W1bt + (size_t)row * 512 + k0 + c * 4);
            uint off = (uint)(row * 128 + c * 8);
            off ^= (uint)((row & 7) << 4);
            *(uint2*)(Bs + off) = val;
        }
        __syncthreads();
        #pragma unroll
        for (int ks = 0; ks < 2; ++ks) {
            uint arow = (uint)(wave * 16 + lr);
            uint aoff = (arow * 128 + (uint)(ks * 64 + lk * 16)) ^ (uint)((lr & 7) << 4);
            bf16x8 av = *(const bf16x8*)(As + aoff);
            #pragma unroll
            for (int f = 0; f < 8; ++f) {
                uint brow = (uint)(f * 16 + lr);
                uint boff = (brow * 128 + (uint)(ks * 64 + lk * 16)) ^ (uint)((lr & 7) << 4);
                bf16x8 bv = *(const bf16x8*)(Bs + boff);
                acc[f] = __builtin_amdgcn_mfma_f32_16x16x32_bf16(av, bv, acc[f], 0, 0, 0);
            }
        }
        __syncthreads();
    }
    #pragma unroll
    for (int f = 0; f < 8; ++f) {
        int nn = f * 16 + lr;
        #pragma unroll
        for (int r = 0; r < 4; ++r) {
            int node = bn + wave * 16 + lk * 4 + r;
            if (node < n) h1bf[(size_t)node * 128 + nn] = (bf16_t)acc[f][r];
        }
    }
    float asv[8], adv[8];
    #pragma unroll
    for (int h = 0; h < 4; ++h) {
        asv[2 * h]     = a_src1[h * 32 + lr];
        asv[2 * h + 1] = a_src1[h * 32 + 16 + lr];
        adv[2 * h]     = a_dst1[h * 32 + lr];
        adv[2 * h + 1] = a_dst1[h * 32 + 16 + lr];
    }
    #pragma unroll
    for (int r = 0; r < 4; ++r) {
        int node = bn + wave * 16 + lk * 4 + r;
        #pragma unroll
        for (int h = 0; h < 4; ++h) {
            float ps = acc[2 * h][r] * asv[2 * h] + acc[2 * h + 1][r] * asv[2 * h + 1];
            float pd = acc[2 * h][r] * adv[2 * h] + acc[2 * h + 1][r] * adv[2 * h + 1];
            #pragma unroll
            for (int m = 8; m >= 1; m >>= 1) {
                ps += __shfl_xor(ps, m, 64);
                pd += __shfl_xor(pd, m, 64);
            }
            if (node < n) {
                if (lr == h)     asrc[node * 4 + h] = ps;
                if (lr == h + 4) adst[node * 4 + h] = pd;
            }
        }
    }
}

// ---------------- GAT1 aggregation (packed uint2 gather) + fused h2/alpha2 ----------------
__global__ __launch_bounds__(128) void k_gat1(const bf16_t* __restrict__ h1bf,
                                              const float* __restrict__ asrc,
                                              const float* __restrict__ adst,
                                              const float* __restrict__ b1,
                                              const unsigned* __restrict__ rowptr,
                                              const ushort* __restrict__ csr16,
                                              const float* __restrict__ W2,
                                              const float* __restrict__ a_src2,
                                              const float* __restrict__ a_dst2,
                                              bf16_t* __restrict__ h2bf,
                                              float* __restrict__ asrc2,
                                              float* __restrict__ adst2, int n) {
    int d = blockIdx.x;
    int tid = threadIdx.x;
    int t = tid & 31, h = tid >> 5;          // staging roles
    unsigned k0 = rowptr[d], k1 = rowptr[d + 1];
    float adh = adst[d * 4 + h];
    __shared__ ushort ss[32];
    __shared__ float ps[4 * 33];             // stride 33: conflict-free head-column reads
    __shared__ float dsh[4];
    __shared__ float pw[32][5];              // wave-1 partials, stride 5
    __shared__ float os[128];
    __shared__ float ps2[128];
    const uint2* h1u2 = (const uint2*)h1bf;

    int c = tid & 31;                        // uint2 col: bf16 cols 4c..4c+3
    int grp = tid >> 5;                      // edge subgroup 0..3
    int hc = c >> 3;                         // head owning my 4 columns
    float a0 = 0.f, a1 = 0.f, a2 = 0.f, a3 = 0.f;
    float den = 0.f;
    for (unsigned kk = k0; kk < k1; kk += 32) {
        unsigned k = kk + t;
        float p = 0.f;
        ushort s = 0;
        if (k < k1) {
            s = csr16[k];
            float v = asrc[(unsigned)s * 4 + h] + adh;
            v = (v > 0.f) ? v : NEG_SLOPE * v;
            p = __expf(v);
        }
        if (h == 0) ss[t] = s;
        ps[h * 33 + t] = p;
        den += p;
        __syncthreads();
        int nk = (int)min(32u, k1 - kk);
        for (int qb = 0; qb < nk; qb += 4) {
            int q = qb + grp;
            float pq = ps[hc * 33 + q];      // 0 for padded edges
            uint2 u = h1u2[(size_t)ss[q] * 32 + c];
            a0 = fmaf(pq, bflo(u.x), a0);
            a1 = fmaf(pq, bfhi(u.x), a1);
            a2 = fmaf(pq, bflo(u.y), a2);
            a3 = fmaf(pq, bfhi(u.y), a3);
        }
        __syncthreads();
    }
    #pragma unroll
    for (int m = 16; m >= 1; m >>= 1) den += __shfl_xor(den, m, 32);
    if (t == 0) dsh[h] = den;
    // combine the 4 edge-subgroups: intra-wave halves, then cross-wave via LDS
    a0 += __shfl_xor(a0, 32, 64);
    a1 += __shfl_xor(a1, 32, 64);
    a2 += __shfl_xor(a2, 32, 64);
    a3 += __shfl_xor(a3, 32, 64);
    if (tid >= 64 && tid < 96) {
        pw[c][0] = a0; pw[c][1] = a1; pw[c][2] = a2; pw[c][3] = a3;
    }
    __syncthreads();
    if (tid < 32) {
        a0 += pw[c][0]; a1 += pw[c][1]; a2 += pw[c][2]; a3 += pw[c][3];
        float inv = 1.f / (dsh[hc] + 1e-16f);
        float4 bb = *(const float4*)(b1 + 4 * c);
        float o0 = a0 * inv + bb.x;
        float o1 = a1 * inv + bb.y;
        float o2 = a2 * inv + bb.z;
        float o3 = a3 * inv + bb.w;
        os[4 * c + 0] = (o0 > 0.f) ? o0 : (__expf(o0) - 1.f);
        os[4 * c + 1] = (o1 > 0.f) ? o1 : (__expf(o1) - 1.f);
        os[4 * c + 2] = (o2 > 0.f) ? o2 : (__expf(o2) - 1.f);
        os[4 * c + 3] = (o3 > 0.f) ? o3 : (__expf(o3) - 1.f);
    }
    __syncthreads();
    // fused h2 = o @ W2 [128x32]
    int j = tid & 31, kc = tid >> 5;
    float part = 0.f;
    #pragma unroll
    for (int i = 0; i < 32; ++i) {
        int k = kc * 32 + i;
        part = fmaf(os[k], W2[k * 32 + j], part);
    }
    ps2[kc * 32 + j] = part;
    __syncthreads();
    if (tid < 32) {
        float h2v = ps2[tid] + ps2[32 + tid] + ps2[64 + tid] + ps2[96 + tid];
        float cs = h2v * a_src2[tid];
        float cd = h2v * a_dst2[tid];
        #pragma unroll
        for (int m = 16; m >= 1; m >>= 1) {
            cs += __shfl_xor(cs, m, 64);
            cd += __shfl_xor(cd, m, 64);
        }
        h2bf[(size_t)d * 32 + tid] = (bf16_t)h2v;
        if (tid == 0) { asrc2[d] = cs; adst2[d] = cd; }
    }
}

// ---------------- GAT2 aggregation (packed uint2 gather, 8 edges in flight) ----------------
__global__ __launch_bounds__(64) void k_gat2(const bf16_t* __restrict__ h2bf,
                                             const float* __restrict__ asrc2,
                                             const float* __restrict__ adst2,
                                             const float* __restrict__ b2,
                                             const unsigned* __restrict__ rowptr,
                                             const ushort* __restrict__ csr16,
                                             float* __restrict__ g, int n) {
    int d = blockIdx.x;
    int tid = threadIdx.x;
    unsigned k0 = rowptr[d], k1 = rowptr[d + 1];
    float adh = adst2[d];
    const uint2* h2u2 = (const uint2*)h2bf;
    __shared__ ushort ss[64];
    __shared__ float ps[64];
    int c = tid & 7, grp = tid >> 3;     // uint2 col / edge subgroup
    float den = 0.f, a0 = 0.f, a1 = 0.f, a2 = 0.f, a3 = 0.f;
    for (unsigned kk = k0; kk < k1; kk += 64) {
        unsigned k = kk + tid;
        float p = 0.f;
        ushort s = 0;
        if (k < k1) {
            s = csr16[k];
            float v = asrc2[s] + adh;
            v = (v > 0.f) ? v : NEG_SLOPE * v;
            p = __expf(v);
        }
        ss[tid] = s;
        ps[tid] = p;
        den += p;
        __syncthreads();
        int nk = (int)min(64u, k1 - kk);
        for (int qb = 0; qb < nk; qb += 8) {
            int q = qb + grp;
            float pq = ps[q];
            uint2 u = h2u2[(size_t)ss[q] * 8 + c];
            a0 = fmaf(pq, bflo(u.x), a0);
            a1 = fmaf(pq, bfhi(u.x), a1);
            a2 = fmaf(pq, bflo(u.y), a2);
            a3 = fmaf(pq, bfhi(u.y), a3);
        }
        __syncthreads();
    }
    #pragma unroll
    for (int m = 32; m >= 1; m >>= 1) den += __shfl_xor(den, m, 64);
    #pragma unroll
    for (int m = 8; m <= 32; m <<= 1) {
        a0 += __shfl_xor(a0, m, 64);
        a1 += __shfl_xor(a1, m, 64);
        a2 += __shfl_xor(a2, m, 64);
        a3 += __shfl_xor(a3, m, 64);
    }
    if (tid < 8) {
        float inv = 1.f / (den + 1e-16f);
        float4 bb = *(const float4*)(b2 + 4 * c);
        float4 val;
        val.x = a0 * inv + bb.x;
        val.y = a1 * inv + bb.y;
        val.z = a2 * inv + bb.z;
        val.w = a3 * inv + bb.w;
        *(float4*)(g + (size_t)d * 32 + 4 * c) = val;
    }
}

// ---------------- MLP (MFMA): out = relu([txt,g]@Wf1+bf1)@Wf2+bf2 ----------------
__global__ __launch_bounds__(256) void k_mlp_mfma(const float* __restrict__ txt,
                                                  const float* __restrict__ g,
                                                  const bf16_t* __restrict__ Wf1bt,
                                                  const float* __restrict__ bf1,
                                                  const float* __restrict__ Wf2,
                                                  const float* __restrict__ bf2,
                                                  float* __restrict__ out, int n) {
    __shared__ char lds[16384];
    char* As = lds;
    char* Bs = lds + 8192;
    int tid = threadIdx.x;
    int bn = blockIdx.x * 64;
    int wave = tid >> 6, lane = tid & 63;
    int lr = lane & 15, lk = lane >> 4;
    f32x4 acc[4] = {};
    const float4* t4 = (const float4*)txt;
    const float4* g4 = (const float4*)g;

    for (int s = 0; s < 13; ++s) {
        int k0 = s * 64;
        #pragma unroll
        for (int i = 0; i < 4; ++i) {
            int v = tid + i * 256;
            int row = v >> 4, c4 = v & 15;
            int node = bn + row;
            int kg = k0 + c4 * 4;
            float4 val = make_float4(0.f, 0.f, 0.f, 0.f);
            if (node < n) {
                if (kg < 768)      val = t4[(size_t)node * 192 + (kg >> 2)];
                else if (kg < 800) val = g4[(size_t)node * 8 + ((kg - 768) >> 2)];
            }
            uint off = (uint)(row * 128 + c4 * 8);
            off ^= (uint)((row & 7) << 4);
            *(uint2*)(As + off) = pack4bf16(val);
        }
        #pragma unroll
        for (int i = 0; i < 4; ++i) {
            int v = tid + i * 256;
            int row = v >> 4, c = v & 15;
            uint2 val = *(const uint2*)(Wf1bt + (size_t)row * 832 + k0 + c * 4);
            uint off = (uint)(row * 128 + c * 8);
            off ^= (uint)((row & 7) << 4);
            *(uint2*)(Bs + off) = val;
        }
        __syncthreads();
        #pragma unroll
        for (int ks = 0; ks < 2; ++ks) {
            uint arow = (uint)(wave * 16 + lr);
            uint aoff = (arow * 128 + (uint)(ks * 64 + lk * 16)) ^ (uint)((lr & 7) << 4);
            bf16x8 av = *(const bf16x8*)(As + aoff);
            #pragma unroll
            for (int f = 0; f < 4; ++f) {
                uint brow = (uint)(f * 16 + lr);
                uint boff = (brow * 128 + (uint)(ks * 64 + lk * 16)) ^ (uint)((lr & 7) << 4);
                bf16x8 bv = *(const bf16x8*)(Bs + boff);
                acc[f] = __builtin_amdgcn_mfma_f32_16x16x32_bf16(av, bv, acc[f], 0, 0, 0);
            }
        }
        __syncthreads();
    }
    float rsum[4] = {0.f, 0.f, 0.f, 0.f};
    #pragma unroll
    for (int f = 0; f < 4; ++f) {
        int nn = f * 16 + lr;
        float bb = bf1[nn], ww = Wf2[nn];
        #pragma unroll
        for (int r = 0; r < 4; ++r) {
            float v = acc[f][r] + bb;
            rsum[r] += fmaxf(v, 0.f) * ww;
        }
    }
    #pragma unroll
    for (int r = 0; r < 4; ++r) {
        #pragma unroll
        for (int m = 8; m >= 1; m >>= 1) rsum[r] += __shfl_xor(rsum[r], m, 64);
        if (lr == 0) {
            int node = bn + wave * 16 + lk * 4 + r;
            if (node < n) out[node] = rsum[r] + bf2[0];
        }
    }
}

extern "C" void kernel_launch(void* const* d_in, const int* in_sizes, int n_in,
                              void* d_out, int out_size, void* d_ws, size_t ws_size,
                              hipStream_t stream) {
    const float* txt    = (const float*)d_in[0];
    const float* x      = (const float*)d_in[1];
    const float* W1     = (const float*)d_in[2];
    const float* a_src1 = (const float*)d_in[3];
    const float* a_dst1 = (const float*)d_in[4];
    const float* b1     = (const float*)d_in[5];
    const float* W2     = (const float*)d_in[6];
    const float* a_src2 = (const float*)d_in[7];
    const float* a_dst2 = (const float*)d_in[8];
    const float* b2     = (const float*)d_in[9];
    const float* Wf1    = (const float*)d_in[10];
    const float* bf1    = (const float*)d_in[11];
    const float* Wf2    = (const float*)d_in[12];
    const float* bf2    = (const float*)d_in[13];
    const int*   ei     = (const int*)d_in[14];

    int n  = in_sizes[1] / 512;
    int E  = in_sizes[14] / 2;
    int ET = E + n;
    int nbuck = (n + 255) >> 8;
    float* out = (float*)d_out;

    char* p = (char*)d_ws;
    auto alloc = [&](size_t bytes) -> char* {
        char* q = p;
        p += (bytes + 255) & ~(size_t)255;
        return q;
    };
    bf16_t*   h1bf   = (bf16_t*)alloc((size_t)n * 128 * 2);
    float*    asrc1  = (float*)alloc((size_t)n * 4 * 4);
    float*    adst1  = (float*)alloc((size_t)n * 4 * 4);
    bf16_t*   h2bf   = (bf16_t*)alloc((size_t)n * 32 * 2);
    float*    asrc2  = (float*)alloc((size_t)n * 4);
    float*    adst2  = (float*)alloc((size_t)n * 4);
    float*    gbuf   = (float*)alloc((size_t)n * 32 * 4);
    unsigned* rowptr = (unsigned*)alloc((size_t)(nbuck * 256 + 1) * 4);
    ushort*   csr16  = (ushort*)alloc((size_t)ET * 2);
    unsigned* gbuck  = (unsigned*)alloc((size_t)nbuck * BCAP * 4);
    unsigned* gcur   = (unsigned*)alloc((size_t)nbuck * 4);
    bf16_t*   W1bt   = (bf16_t*)alloc((size_t)128 * 512 * 2);
    bf16_t*   Wf1bt  = (bf16_t*)alloc((size_t)64 * 832 * 2);

    hipMemsetAsync(gcur, 0, (size_t)nbuck * 4, stream);

    k_w1t<<<256, 256, 0, stream>>>(W1, W1bt);
    k_wf1t<<<208, 256, 0, stream>>>(Wf1, Wf1bt);

    int ntiles = (ET + 4095) / 4096;
    k_bucket<<<ntiles, 256, 0, stream>>>(ei, E, n, nbuck, gcur, gbuck);
    k_finecsr<<<nbuck, 256, 0, stream>>>(gcur, gbuck, nbuck, rowptr, csr16);

    int nb64 = (n + 63) / 64;
    k_gemm1_mfma<<<nb64, 256, 0, stream>>>(x, W1bt, a_src1, a_dst1, h1bf, asrc1, adst1, n);
    k_gat1<<<n, 128, 0, stream>>>(h1bf, asrc1, adst1, b1, rowptr, csr16,
                                  W2, a_src2, a_dst2, h2bf, asrc2, adst2, n);
    k_gat2<<<n, 64, 0, stream>>>(h2bf, asrc2, adst2, b2, rowptr, csr16, gbuf, n);
    k_mlp_mfma<<<nb64, 256, 0, stream>>>(txt, gbuf, Wf1bt, bf1, Wf2, bf2, out, n);
}